// Round 3
// baseline (515.985 us; speedup 1.0000x reference)
//
#include <hip/hip_runtime.h>

#define DIM 128
#define BN_EPS 1e-5f

// ---------------------------------------------------------------------------
// init: zero degree counters and BN stats accumulators
__global__ __launch_bounds__(256) void k_init(int* __restrict__ deg_cnt,
                                              float* __restrict__ stats, int n) {
    int i = blockIdx.x * 256 + threadIdx.x;
    if (i < n) deg_cnt[i] = 0;
    if (i < 512) stats[i] = 0.0f;
}

// in-degree histogram over dst
__global__ __launch_bounds__(256) void k_deg(const int* __restrict__ dst,
                                             int* __restrict__ deg_cnt, int e) {
    int i = blockIdx.x * 256 + threadIdx.x;
    if (i < e) atomicAdd(&deg_cnt[dst[i]], 1);
}

// dinv[i] = rsqrt(deg_cnt[i] + 1)   (self-loop adds 1)
__global__ __launch_bounds__(256) void k_dinv(const int* __restrict__ deg_cnt,
                                              float* __restrict__ dinv, int n) {
    int i = blockIdx.x * 256 + threadIdx.x;
    if (i < n) dinv[i] = rsqrtf((float)deg_cnt[i] + 1.0f);
}

// ---------------------------------------------------------------------------
// hierarchical exclusive scan (all 256-thread blocks)
__device__ __forceinline__ int wave_scan_incl(int v) {
    int lane = threadIdx.x & 63;
#pragma unroll
    for (int off = 1; off < 64; off <<= 1) {
        int t = __shfl_up(v, off, 64);
        if (lane >= off) v += t;
    }
    return v;
}

// stage 1: per-block local exclusive scan -> row_start; block totals -> blk_sum
__global__ __launch_bounds__(256) void k_scan1(const int* __restrict__ deg_cnt,
                                               int* __restrict__ row_start,
                                               int* __restrict__ blk_sum, int n) {
    int tid = threadIdx.x;
    int i = blockIdx.x * 256 + tid;
    int v = (i < n) ? deg_cnt[i] : 0;
    int inc = wave_scan_incl(v);
    __shared__ int wtot[4];
    int wave = tid >> 6, lane = tid & 63;
    if (lane == 63) wtot[wave] = inc;
    __syncthreads();
    int woff = 0;
    for (int w = 0; w < wave; ++w) woff += wtot[w];
    int excl = woff + inc - v;
    if (i < n) row_start[i] = excl;
    if (tid == 255) blk_sum[blockIdx.x] = woff + inc;
}

// stage 2: single block scans blk_sum (nblk <= 256) -> blk_off; total -> row_start[n]
__global__ __launch_bounds__(256) void k_scan2(const int* __restrict__ blk_sum,
                                               int* __restrict__ blk_off,
                                               int* __restrict__ row_start,
                                               int nblk, int n) {
    int tid = threadIdx.x;
    int v = (tid < nblk) ? blk_sum[tid] : 0;
    int inc = wave_scan_incl(v);
    __shared__ int wtot[4];
    int wave = tid >> 6, lane = tid & 63;
    if (lane == 63) wtot[wave] = inc;
    __syncthreads();
    int woff = 0;
    for (int w = 0; w < wave; ++w) woff += wtot[w];
    if (tid < nblk) blk_off[tid] = woff + inc - v;
    if (tid == 255) row_start[n] = woff + inc;   // grand total
}

// stage 3: add block offsets in place; mirror into cursor
__global__ __launch_bounds__(256) void k_scan3(int* __restrict__ row_start,
                                               const int* __restrict__ blk_off,
                                               int* __restrict__ cursor, int n) {
    int i = blockIdx.x * 256 + threadIdx.x;
    if (i < n) {
        int rs = row_start[i] + blk_off[blockIdx.x];
        row_start[i] = rs;
        cursor[i] = rs;
    }
}

// scatter edges into CSR slots: col = src node, wgt = dinv[src]*dinv[dst]
__global__ __launch_bounds__(256) void k_fill(const int* __restrict__ src,
                                              const int* __restrict__ dst,
                                              const float* __restrict__ dinv,
                                              int* __restrict__ cursor,
                                              int* __restrict__ col,
                                              float* __restrict__ wgt, int e) {
    int i = blockIdx.x * 256 + threadIdx.x;
    if (i < e) {
        int s = src[i], t = dst[i];
        int pos = atomicAdd(&cursor[t], 1);
        col[pos] = s;
        wgt[pos] = dinv[s] * dinv[t];
    }
}

// ---------------------------------------------------------------------------
// H = X @ W   (X: [n,128], W: [128,128] row-major)
// block: 256 thr, tile 32 rows x 128 cols; K split in two 64-wide halves so
// LDS = 32 KB (W half) + 8 KB (X half-tile) = 40 KB (< 64 KB limit).
__global__ __launch_bounds__(256) void k_gemm(const float* __restrict__ X,
                                              const float* __restrict__ W,
                                              float* __restrict__ H, int n) {
    __shared__ float ws[64 * DIM];   // 32 KB: W rows kh*64 .. kh*64+63
    __shared__ float xs[32 * 64];    // 8 KB: X tile, k-cols kh*64 .. kh*64+63
    int t = threadIdx.x;
    int r0b = blockIdx.x * 32;
    int ty = t >> 5;          // 0..7 -> 4-row group
    int tx = t & 31;          // 0..31 -> 4-col group
    int r0 = ty * 4;
    int c0 = tx * 4;
    float acc[4][4] = {};

    const float4* W4 = (const float4*)W;
    const float4* X4 = (const float4*)X;
    float4* ws4 = (float4*)ws;
    float4* xs4 = (float4*)xs;

    for (int kh = 0; kh < 2; ++kh) {
        if (kh) __syncthreads();   // finish compute on half 0 before overwrite
#pragma unroll
        for (int i = 0; i < 8; ++i) {
            int idx = t + 256 * i;                 // 0..2047 float4s = 32 KB
            ws4[idx] = W4[kh * 2048 + idx];
        }
#pragma unroll
        for (int i = 0; i < 2; ++i) {
            int f = t + 256 * i;                   // 0..511 float4s = 8 KB
            int row = f >> 4;                      // 0..31
            int cg  = f & 15;                      // float4 within 64-col half
            float4 v = make_float4(0.f, 0.f, 0.f, 0.f);
            if (r0b + row < n) v = X4[(size_t)(r0b + row) * 32 + kh * 16 + cg];
            xs4[f] = v;
        }
        __syncthreads();
#pragma unroll 4
        for (int k = 0; k < 64; ++k) {
            float4 b = *(const float4*)&ws[k * DIM + c0];
            float a0 = xs[(r0 + 0) * 64 + k];
            float a1 = xs[(r0 + 1) * 64 + k];
            float a2 = xs[(r0 + 2) * 64 + k];
            float a3 = xs[(r0 + 3) * 64 + k];
            acc[0][0] += a0 * b.x; acc[0][1] += a0 * b.y; acc[0][2] += a0 * b.z; acc[0][3] += a0 * b.w;
            acc[1][0] += a1 * b.x; acc[1][1] += a1 * b.y; acc[1][2] += a1 * b.z; acc[1][3] += a1 * b.w;
            acc[2][0] += a2 * b.x; acc[2][1] += a2 * b.y; acc[2][2] += a2 * b.z; acc[2][3] += a2 * b.w;
            acc[3][0] += a3 * b.x; acc[3][1] += a3 * b.y; acc[3][2] += a3 * b.z; acc[3][3] += a3 * b.w;
        }
    }
#pragma unroll
    for (int i = 0; i < 4; ++i) {
        int row = r0b + r0 + i;
        if (row < n) {
            *(float4*)&H[(size_t)row * DIM + c0] =
                make_float4(acc[i][0], acc[i][1], acc[i][2], acc[i][3]);
        }
    }
}

// ---------------------------------------------------------------------------
// out[i,:] = sum_{j in in-edges(i)} H[col[j],:]*wgt[j] + H[i,:]*dinv[i]^2 + bias
// one node per 128 threads (2 nodes / 256-thr block)
__global__ __launch_bounds__(256) void k_agg(const float* __restrict__ H,
                                             const float* __restrict__ bias,
                                             const float* __restrict__ dinv,
                                             const int* __restrict__ row_start,
                                             const int* __restrict__ col,
                                             const float* __restrict__ wgt,
                                             float* __restrict__ out, int n) {
    int node = blockIdx.x * 2 + (threadIdx.x >> 7);
    int d = threadIdx.x & 127;
    if (node >= n) return;
    float di = dinv[node];
    float acc = H[(size_t)node * DIM + d] * (di * di) + bias[d];
    int jb = row_start[node], je = row_start[node + 1];
    int j = jb;
    for (; j + 1 < je; j += 2) {
        int s0 = col[j], s1 = col[j + 1];
        float w0 = wgt[j], w1 = wgt[j + 1];
        float h0 = H[(size_t)s0 * DIM + d];
        float h1 = H[(size_t)s1 * DIM + d];
        acc += h0 * w0;
        acc += h1 * w1;
    }
    if (j < je) acc += H[(size_t)col[j] * DIM + d] * wgt[j];
    out[(size_t)node * DIM + d] = acc;
}

// ---------------------------------------------------------------------------
// column sums + sums of squares -> sums[0..127]=sum, sums[128..255]=sumsq
__global__ __launch_bounds__(256) void k_stats(const float* __restrict__ V,
                                               float* __restrict__ sums, int n) {
    int d = threadIdx.x & 127;
    int half = threadIdx.x >> 7;
    int r0 = blockIdx.x * 256;
    int r1 = min(r0 + 256, n);
    float s = 0.f, q = 0.f;
    for (int r = r0 + half; r < r1; r += 2) {
        float v = V[(size_t)r * DIM + d];
        s += v; q += v * v;
    }
    __shared__ float ls[256], lq[256];
    ls[threadIdx.x] = s; lq[threadIdx.x] = q;
    __syncthreads();
    if (half == 0) {
        atomicAdd(&sums[d], s + ls[threadIdx.x + 128]);
        atomicAdd(&sums[128 + d], q + lq[threadIdx.x + 128]);
    }
}

// BN (training-mode batch stats) + ReLU, in place
__global__ __launch_bounds__(256) void k_bn_relu(float* __restrict__ V,
                                                 const float* __restrict__ sums,
                                                 const float* __restrict__ gamma,
                                                 const float* __restrict__ beta,
                                                 int n, float invN) {
    int idx = blockIdx.x * 256 + threadIdx.x;
    if (idx >= n * DIM) return;
    int d = idx & 127;
    float mu = sums[d] * invN;
    float var = sums[128 + d] * invN - mu * mu;
    float inv = rsqrtf(var + BN_EPS);
    float scale = gamma[d] * inv;
    float shift = beta[d] - mu * scale;
    float v = V[idx] * scale + shift;
    V[idx] = fmaxf(v, 0.f);
}

// BN + residual + ReLU -> out (safe when V == out: element-wise in place)
__global__ __launch_bounds__(256) void k_bn_res_relu(const float* __restrict__ V,
                                                     const float* __restrict__ X,
                                                     const float* __restrict__ sums,
                                                     const float* __restrict__ gamma,
                                                     const float* __restrict__ beta,
                                                     float* __restrict__ out,
                                                     int n, float invN) {
    int idx = blockIdx.x * 256 + threadIdx.x;
    if (idx >= n * DIM) return;
    int d = idx & 127;
    float mu = sums[d] * invN;
    float var = sums[128 + d] * invN - mu * mu;
    float inv = rsqrtf(var + BN_EPS);
    float scale = gamma[d] * inv;
    float shift = beta[d] - mu * scale;
    float v = V[idx] * scale + shift + X[idx];
    out[idx] = fmaxf(v, 0.f);
}

// ---------------------------------------------------------------------------
extern "C" void kernel_launch(void* const* d_in, const int* in_sizes, int n_in,
                              void* d_out, int out_size, void* d_ws, size_t ws_size,
                              hipStream_t stream) {
    const float* x      = (const float*)d_in[0];
    const int*   ei     = (const int*)d_in[1];
    const float* W1     = (const float*)d_in[2];
    const float* b1     = (const float*)d_in[3];
    const float* gamma1 = (const float*)d_in[4];
    const float* beta1  = (const float*)d_in[5];
    const float* W2     = (const float*)d_in[6];
    const float* b2     = (const float*)d_in[7];
    const float* gamma2 = (const float*)d_in[8];
    const float* beta2  = (const float*)d_in[9];
    float* out = (float*)d_out;

    int n = in_sizes[0] / DIM;   // 50000
    int e = in_sizes[1] / 2;     // 800000
    const int* srcIdx = ei;       // edge_index[0,:]
    const int* dstIdx = ei + e;   // edge_index[1,:]

    int gN    = (n + 255) / 256;
    int gE    = (e + 255) / 256;
    int gRows = (n + 31) / 32;
    int gNode = (n + 1) / 2;
    int gElem = (n * DIM + 255) / 256;
    float invN = 1.0f / (float)n;

    char* ws = (char*)d_ws;
    size_t off = 0;
    auto alloc = [&](size_t bytes) -> void* {
        void* p = ws + off;
        off += (bytes + 255) & ~(size_t)255;
        return p;
    };
    int*   deg_cnt   = (int*)  alloc((size_t)n * 4);
    float* dinv      = (float*)alloc((size_t)n * 4);
    int*   row_start = (int*)  alloc((size_t)(n + 1) * 4);
    int*   cursor    = (int*)  alloc((size_t)n * 4);
    int*   blk_sum   = (int*)  alloc((size_t)gN * 4);
    int*   blk_off   = (int*)  alloc((size_t)gN * 4);
    int*   col       = (int*)  alloc((size_t)e * 4);
    float* wgt       = (float*)alloc((size_t)e * 4);
    float* bufA      = (float*)alloc((size_t)n * DIM * 4);
    float* stats     = (float*)alloc(512 * 4);   // [stats1 | stats2]
    float* stats1 = stats;
    float* stats2 = stats + 256;
    // d_out doubles as the second N x D buffer (fully overwritten at the end,
    // final BN pass is element-wise in-place-safe).
    float* bufB = out;

    // workspace guard: fail cleanly (wrong output) instead of corrupting memory
    if (off > ws_size || gN > 256) return;

    // graph preprocessing: degrees -> dinv -> CSR
    k_init<<<gN, 256, 0, stream>>>(deg_cnt, stats, n);
    k_deg<<<gE, 256, 0, stream>>>(dstIdx, deg_cnt, e);
    k_dinv<<<gN, 256, 0, stream>>>(deg_cnt, dinv, n);
    k_scan1<<<gN, 256, 0, stream>>>(deg_cnt, row_start, blk_sum, n);
    k_scan2<<<1, 256, 0, stream>>>(blk_sum, blk_off, row_start, gN, n);
    k_scan3<<<gN, 256, 0, stream>>>(row_start, blk_off, cursor, n);
    k_fill<<<gE, 256, 0, stream>>>(srcIdx, dstIdx, dinv, cursor, col, wgt, e);

    // conv1 + BN + ReLU
    k_gemm<<<gRows, 256, 0, stream>>>(x, W1, bufA, n);
    k_agg<<<gNode, 256, 0, stream>>>(bufA, b1, dinv, row_start, col, wgt, bufB, n);
    k_stats<<<gN, 256, 0, stream>>>(bufB, stats1, n);
    k_bn_relu<<<gElem, 256, 0, stream>>>(bufB, stats1, gamma1, beta1, n, invN);

    // conv2 + BN + residual + ReLU
    k_gemm<<<gRows, 256, 0, stream>>>(bufB, W2, bufA, n);
    k_agg<<<gNode, 256, 0, stream>>>(bufA, b2, dinv, row_start, col, wgt, bufB, n);
    k_stats<<<gN, 256, 0, stream>>>(bufB, stats2, n);
    k_bn_res_relu<<<gElem, 256, 0, stream>>>(bufB, x, stats2, gamma2, beta2, out, n, invN);
}

// Round 7
// 481.975 us; speedup vs baseline: 1.0706x; 1.0706x over previous
//
#include <hip/hip_runtime.h>

#define DIM 128
#define BN_EPS 1e-5f

// ---------------------------------------------------------------------------
// init: zero degree counters and BN stats accumulators
__global__ __launch_bounds__(256) void k_init(int* __restrict__ deg_cnt,
                                              float* __restrict__ stats, int n) {
    int i = blockIdx.x * 256 + threadIdx.x;
    if (i < n) deg_cnt[i] = 0;
    if (i < 512) stats[i] = 0.0f;
}

// in-degree histogram over dst
__global__ __launch_bounds__(256) void k_deg(const int* __restrict__ dst,
                                             int* __restrict__ deg_cnt, int e) {
    int i = blockIdx.x * 256 + threadIdx.x;
    if (i < e) atomicAdd(&deg_cnt[dst[i]], 1);
}

// dinv[i] = rsqrt(deg_cnt[i] + 1)   (self-loop adds 1)
__global__ __launch_bounds__(256) void k_dinv(const int* __restrict__ deg_cnt,
                                              float* __restrict__ dinv, int n) {
    int i = blockIdx.x * 256 + threadIdx.x;
    if (i < n) dinv[i] = rsqrtf((float)deg_cnt[i] + 1.0f);
}

// ---------------------------------------------------------------------------
// hierarchical exclusive scan (all 256-thread blocks)
__device__ __forceinline__ int wave_scan_incl(int v) {
    int lane = threadIdx.x & 63;
#pragma unroll
    for (int off = 1; off < 64; off <<= 1) {
        int t = __shfl_up(v, off, 64);
        if (lane >= off) v += t;
    }
    return v;
}

// stage 1: per-block local exclusive scan -> row_start; block totals -> blk_sum
__global__ __launch_bounds__(256) void k_scan1(const int* __restrict__ deg_cnt,
                                               int* __restrict__ row_start,
                                               int* __restrict__ blk_sum, int n) {
    int tid = threadIdx.x;
    int i = blockIdx.x * 256 + tid;
    int v = (i < n) ? deg_cnt[i] : 0;
    int inc = wave_scan_incl(v);
    __shared__ int wtot[4];
    int wave = tid >> 6, lane = tid & 63;
    if (lane == 63) wtot[wave] = inc;
    __syncthreads();
    int woff = 0;
    for (int w = 0; w < wave; ++w) woff += wtot[w];
    int excl = woff + inc - v;
    if (i < n) row_start[i] = excl;
    if (tid == 255) blk_sum[blockIdx.x] = woff + inc;
}

// stage 2: single block scans blk_sum (nblk <= 256) -> blk_off; total -> row_start[n]
__global__ __launch_bounds__(256) void k_scan2(const int* __restrict__ blk_sum,
                                               int* __restrict__ blk_off,
                                               int* __restrict__ row_start,
                                               int nblk, int n) {
    int tid = threadIdx.x;
    int v = (tid < nblk) ? blk_sum[tid] : 0;
    int inc = wave_scan_incl(v);
    __shared__ int wtot[4];
    int wave = tid >> 6, lane = tid & 63;
    if (lane == 63) wtot[wave] = inc;
    __syncthreads();
    int woff = 0;
    for (int w = 0; w < wave; ++w) woff += wtot[w];
    if (tid < nblk) blk_off[tid] = woff + inc - v;
    if (tid == 255) row_start[n] = woff + inc;   // grand total
}

// stage 3: add block offsets in place; mirror into cursor
__global__ __launch_bounds__(256) void k_scan3(int* __restrict__ row_start,
                                               const int* __restrict__ blk_off,
                                               int* __restrict__ cursor, int n) {
    int i = blockIdx.x * 256 + threadIdx.x;
    if (i < n) {
        int rs = row_start[i] + blk_off[blockIdx.x];
        row_start[i] = rs;
        cursor[i] = rs;
    }
}

// scatter edges into CSR slots: col = src node, wgt = dinv[src]*dinv[dst]
__global__ __launch_bounds__(256) void k_fill(const int* __restrict__ src,
                                              const int* __restrict__ dst,
                                              const float* __restrict__ dinv,
                                              int* __restrict__ cursor,
                                              int* __restrict__ col,
                                              float* __restrict__ wgt, int e) {
    int i = blockIdx.x * 256 + threadIdx.x;
    if (i < e) {
        int s = src[i], t = dst[i];
        int pos = atomicAdd(&cursor[t], 1);
        col[pos] = s;
        wgt[pos] = dinv[s] * dinv[t];
    }
}

// ---------------------------------------------------------------------------
// H = X @ W   (X: [n,128], W: [128,128] row-major)
// block: 256 thr, tile 32 rows x 128 cols; K split in two 64-wide halves so
// LDS = 32 KB (W half) + 8 KB (X half-tile) = 40 KB (< 64 KB limit).
__global__ __launch_bounds__(256) void k_gemm(const float* __restrict__ X,
                                              const float* __restrict__ W,
                                              float* __restrict__ H, int n) {
    __shared__ float ws[64 * DIM];   // 32 KB: W rows kh*64 .. kh*64+63
    __shared__ float xs[32 * 64];    // 8 KB: X tile, k-cols kh*64 .. kh*64+63
    int t = threadIdx.x;
    int r0b = blockIdx.x * 32;
    int ty = t >> 5;          // 0..7 -> 4-row group
    int tx = t & 31;          // 0..31 -> 4-col group
    int r0 = ty * 4;
    int c0 = tx * 4;
    float acc[4][4] = {};

    const float4* W4 = (const float4*)W;
    const float4* X4 = (const float4*)X;
    float4* ws4 = (float4*)ws;
    float4* xs4 = (float4*)xs;

    for (int kh = 0; kh < 2; ++kh) {
        if (kh) __syncthreads();   // finish compute on half 0 before overwrite
#pragma unroll
        for (int i = 0; i < 8; ++i) {
            int idx = t + 256 * i;                 // 0..2047 float4s = 32 KB
            ws4[idx] = W4[kh * 2048 + idx];
        }
#pragma unroll
        for (int i = 0; i < 2; ++i) {
            int f = t + 256 * i;                   // 0..511 float4s = 8 KB
            int row = f >> 4;                      // 0..31
            int cg  = f & 15;                      // float4 within 64-col half
            float4 v = make_float4(0.f, 0.f, 0.f, 0.f);
            if (r0b + row < n) v = X4[(size_t)(r0b + row) * 32 + kh * 16 + cg];
            xs4[f] = v;
        }
        __syncthreads();
#pragma unroll 4
        for (int k = 0; k < 64; ++k) {
            float4 b = *(const float4*)&ws[k * DIM + c0];
            float a0 = xs[(r0 + 0) * 64 + k];
            float a1 = xs[(r0 + 1) * 64 + k];
            float a2 = xs[(r0 + 2) * 64 + k];
            float a3 = xs[(r0 + 3) * 64 + k];
            acc[0][0] += a0 * b.x; acc[0][1] += a0 * b.y; acc[0][2] += a0 * b.z; acc[0][3] += a0 * b.w;
            acc[1][0] += a1 * b.x; acc[1][1] += a1 * b.y; acc[1][2] += a1 * b.z; acc[1][3] += a1 * b.w;
            acc[2][0] += a2 * b.x; acc[2][1] += a2 * b.y; acc[2][2] += a2 * b.z; acc[2][3] += a2 * b.w;
            acc[3][0] += a3 * b.x; acc[3][1] += a3 * b.y; acc[3][2] += a3 * b.z; acc[3][3] += a3 * b.w;
        }
    }
#pragma unroll
    for (int i = 0; i < 4; ++i) {
        int row = r0b + r0 + i;
        if (row < n) {
            *(float4*)&H[(size_t)row * DIM + c0] =
                make_float4(acc[i][0], acc[i][1], acc[i][2], acc[i][3]);
        }
    }
}

// ---------------------------------------------------------------------------
// out[i,:] = sum_{j in in-edges(i)} H[col[j],:]*wgt[j] + H[i,:]*dinv[i]^2 + bias
// one node per 128 threads (2 nodes / 256-thr block); 4-edge unroll for MLP
__global__ __launch_bounds__(256) void k_agg(const float* __restrict__ H,
                                             const float* __restrict__ bias,
                                             const float* __restrict__ dinv,
                                             const int* __restrict__ row_start,
                                             const int* __restrict__ col,
                                             const float* __restrict__ wgt,
                                             float* __restrict__ out, int n, int e) {
    int node = blockIdx.x * 2 + (threadIdx.x >> 7);
    int d = threadIdx.x & 127;
    if (node >= n) return;
    float di = dinv[node];
    float acc = H[(size_t)node * DIM + d] * (di * di) + bias[d];
    int jb = row_start[node], je = row_start[node + 1];
    jb = min(max(jb, 0), e);          // clamp: garbage can't cause hang/OOB
    je = min(max(je, jb), e);
    int j = jb;
    for (; j + 4 <= je; j += 4) {
        int   c0 = col[j],     c1 = col[j + 1], c2 = col[j + 2], c3 = col[j + 3];
        float w0 = wgt[j],     w1 = wgt[j + 1], w2 = wgt[j + 2], w3 = wgt[j + 3];
        float h0 = H[(size_t)c0 * DIM + d];
        float h1 = H[(size_t)c1 * DIM + d];
        float h2 = H[(size_t)c2 * DIM + d];
        float h3 = H[(size_t)c3 * DIM + d];
        acc += h0 * w0;
        acc += h1 * w1;
        acc += h2 * w2;
        acc += h3 * w3;
    }
    for (; j < je; ++j) acc += H[(size_t)col[j] * DIM + d] * wgt[j];
    out[(size_t)node * DIM + d] = acc;
}

// ---------------------------------------------------------------------------
// column sums + sums of squares -> sums[0..127]=sum, sums[128..255]=sumsq
__global__ __launch_bounds__(256) void k_stats(const float* __restrict__ V,
                                               float* __restrict__ sums, int n) {
    int d = threadIdx.x & 127;
    int half = threadIdx.x >> 7;
    int r0 = blockIdx.x * 256;
    int r1 = min(r0 + 256, n);
    float s = 0.f, q = 0.f;
    for (int r = r0 + half; r < r1; r += 2) {
        float v = V[(size_t)r * DIM + d];
        s += v; q += v * v;
    }
    __shared__ float ls[256], lq[256];
    ls[threadIdx.x] = s; lq[threadIdx.x] = q;
    __syncthreads();
    if (half == 0) {
        atomicAdd(&sums[d], s + ls[threadIdx.x + 128]);
        atomicAdd(&sums[128 + d], q + lq[threadIdx.x + 128]);
    }
}

// BN (training-mode batch stats) + ReLU, in place
__global__ __launch_bounds__(256) void k_bn_relu(float* __restrict__ V,
                                                 const float* __restrict__ sums,
                                                 const float* __restrict__ gamma,
                                                 const float* __restrict__ beta,
                                                 int n, float invN) {
    int idx = blockIdx.x * 256 + threadIdx.x;
    if (idx >= n * DIM) return;
    int d = idx & 127;
    float mu = sums[d] * invN;
    float var = sums[128 + d] * invN - mu * mu;
    float inv = rsqrtf(var + BN_EPS);
    float scale = gamma[d] * inv;
    float shift = beta[d] - mu * scale;
    float v = V[idx] * scale + shift;
    V[idx] = fmaxf(v, 0.f);
}

// BN + residual + ReLU -> out (element-wise; safe when V == out)
__global__ __launch_bounds__(256) void k_bn_res_relu(const float* __restrict__ V,
                                                     const float* __restrict__ X,
                                                     const float* __restrict__ sums,
                                                     const float* __restrict__ gamma,
                                                     const float* __restrict__ beta,
                                                     float* __restrict__ out,
                                                     int n, float invN) {
    int idx = blockIdx.x * 256 + threadIdx.x;
    if (idx >= n * DIM) return;
    int d = idx & 127;
    float mu = sums[d] * invN;
    float var = sums[128 + d] * invN - mu * mu;
    float inv = rsqrtf(var + BN_EPS);
    float scale = gamma[d] * inv;
    float shift = beta[d] - mu * scale;
    float v = V[idx] * scale + shift + X[idx];
    out[idx] = fmaxf(v, 0.f);
}

// ---------------------------------------------------------------------------
extern "C" void kernel_launch(void* const* d_in, const int* in_sizes, int n_in,
                              void* d_out, int out_size, void* d_ws, size_t ws_size,
                              hipStream_t stream) {
    const float* x      = (const float*)d_in[0];
    const int*   ei     = (const int*)d_in[1];
    const float* W1     = (const float*)d_in[2];
    const float* b1     = (const float*)d_in[3];
    const float* gamma1 = (const float*)d_in[4];
    const float* beta1  = (const float*)d_in[5];
    const float* W2     = (const float*)d_in[6];
    const float* b2     = (const float*)d_in[7];
    const float* gamma2 = (const float*)d_in[8];
    const float* beta2  = (const float*)d_in[9];
    float* out = (float*)d_out;

    int n = in_sizes[0] / DIM;   // 50000
    int e = in_sizes[1] / 2;     // 800000
    const int* srcIdx = ei;       // edge_index[0,:]
    const int* dstIdx = ei + e;   // edge_index[1,:]

    int gN    = (n + 255) / 256;
    int gE    = (e + 255) / 256;
    int gRows = (n + 31) / 32;
    int gNode = (n + 1) / 2;
    int gElem = (n * DIM + 255) / 256;
    float invN = 1.0f / (float)n;

    char* ws = (char*)d_ws;
    size_t off = 0;
    auto alloc = [&](size_t bytes) -> void* {
        void* p = ws + off;
        off += (bytes + 255) & ~(size_t)255;
        return p;
    };
    int*   deg_cnt   = (int*)  alloc((size_t)n * 4);
    float* dinv      = (float*)alloc((size_t)n * 4);
    int*   row_start = (int*)  alloc((size_t)(n + 1) * 4);
    int*   cursor    = (int*)  alloc((size_t)n * 4);
    int*   blk_sum   = (int*)  alloc((size_t)gN * 4);
    int*   blk_off   = (int*)  alloc((size_t)gN * 4);
    int*   col       = (int*)  alloc((size_t)e * 4);
    float* wgt       = (float*)alloc((size_t)e * 4);
    float* bufA      = (float*)alloc((size_t)n * DIM * 4);
    float* stats     = (float*)alloc(512 * 4);   // [stats1 | stats2]
    float* stats1 = stats;
    float* stats2 = stats + 256;
    // d_out doubles as the second N x D buffer (fully overwritten at the end,
    // final BN pass is element-wise in-place-safe).
    float* bufB = out;

    // workspace guard: fail cleanly (wrong output) instead of corrupting memory
    if (off > ws_size || gN > 256) return;

    // graph preprocessing: degrees -> dinv -> CSR
    k_init<<<gN, 256, 0, stream>>>(deg_cnt, stats, n);
    k_deg<<<gE, 256, 0, stream>>>(dstIdx, deg_cnt, e);
    k_dinv<<<gN, 256, 0, stream>>>(deg_cnt, dinv, n);
    k_scan1<<<gN, 256, 0, stream>>>(deg_cnt, row_start, blk_sum, n);
    k_scan2<<<1, 256, 0, stream>>>(blk_sum, blk_off, row_start, gN, n);
    k_scan3<<<gN, 256, 0, stream>>>(row_start, blk_off, cursor, n);
    k_fill<<<gE, 256, 0, stream>>>(srcIdx, dstIdx, dinv, cursor, col, wgt, e);

    // conv1 + BN + ReLU
    k_gemm<<<gRows, 256, 0, stream>>>(x, W1, bufA, n);
    k_agg<<<gNode, 256, 0, stream>>>(bufA, b1, dinv, row_start, col, wgt, bufB, n, e);
    k_stats<<<gN, 256, 0, stream>>>(bufB, stats1, n);
    k_bn_relu<<<gElem, 256, 0, stream>>>(bufB, stats1, gamma1, beta1, n, invN);

    // conv2 + BN + residual + ReLU
    k_gemm<<<gRows, 256, 0, stream>>>(bufB, W2, bufA, n);
    k_agg<<<gNode, 256, 0, stream>>>(bufA, b2, dinv, row_start, col, wgt, bufB, n, e);
    k_stats<<<gN, 256, 0, stream>>>(bufB, stats2, n);
    k_bn_res_relu<<<gElem, 256, 0, stream>>>(bufB, x, stats2, gamma2, beta2, out, n, invN);
}

// Round 8
// 461.902 us; speedup vs baseline: 1.1171x; 1.0435x over previous
//
#include <hip/hip_runtime.h>

#define DIM 128
#define BN_EPS 1e-5f

// ---- bf16 helpers ----
__device__ __forceinline__ float bf2f(unsigned short h) {
    return __uint_as_float(((unsigned int)h) << 16);
}
__device__ __forceinline__ unsigned int f2bf(float f) {
    unsigned int u = __float_as_uint(f);
    return (u + 0x7fffu + ((u >> 16) & 1u)) >> 16;   // round-to-nearest-even
}
__device__ __forceinline__ unsigned int pack2(float a, float b) {
    return f2bf(a) | (f2bf(b) << 16);
}

// ---------------------------------------------------------------------------
// init: zero degree counters and BN stats accumulators
__global__ __launch_bounds__(256) void k_init(int* __restrict__ deg_cnt,
                                              float* __restrict__ stats, int n) {
    int i = blockIdx.x * 256 + threadIdx.x;
    if (i < n) deg_cnt[i] = 0;
    if (i < 512) stats[i] = 0.0f;
}

// in-degree histogram over dst
__global__ __launch_bounds__(256) void k_deg(const int* __restrict__ dst,
                                             int* __restrict__ deg_cnt, int e) {
    int i = blockIdx.x * 256 + threadIdx.x;
    if (i < e) atomicAdd(&deg_cnt[dst[i]], 1);
}

// dinv[i] = rsqrt(deg_cnt[i] + 1)   (self-loop adds 1)
__global__ __launch_bounds__(256) void k_dinv(const int* __restrict__ deg_cnt,
                                              float* __restrict__ dinv, int n) {
    int i = blockIdx.x * 256 + threadIdx.x;
    if (i < n) dinv[i] = rsqrtf((float)deg_cnt[i] + 1.0f);
}

// ---------------------------------------------------------------------------
// hierarchical exclusive scan (all 256-thread blocks)
__device__ __forceinline__ int wave_scan_incl(int v) {
    int lane = threadIdx.x & 63;
#pragma unroll
    for (int off = 1; off < 64; off <<= 1) {
        int t = __shfl_up(v, off, 64);
        if (lane >= off) v += t;
    }
    return v;
}

__global__ __launch_bounds__(256) void k_scan1(const int* __restrict__ deg_cnt,
                                               int* __restrict__ row_start,
                                               int* __restrict__ blk_sum, int n) {
    int tid = threadIdx.x;
    int i = blockIdx.x * 256 + tid;
    int v = (i < n) ? deg_cnt[i] : 0;
    int inc = wave_scan_incl(v);
    __shared__ int wtot[4];
    int wave = tid >> 6, lane = tid & 63;
    if (lane == 63) wtot[wave] = inc;
    __syncthreads();
    int woff = 0;
    for (int w = 0; w < wave; ++w) woff += wtot[w];
    int excl = woff + inc - v;
    if (i < n) row_start[i] = excl;
    if (tid == 255) blk_sum[blockIdx.x] = woff + inc;
}

__global__ __launch_bounds__(256) void k_scan2(const int* __restrict__ blk_sum,
                                               int* __restrict__ blk_off,
                                               int* __restrict__ row_start,
                                               int nblk, int n) {
    int tid = threadIdx.x;
    int v = (tid < nblk) ? blk_sum[tid] : 0;
    int inc = wave_scan_incl(v);
    __shared__ int wtot[4];
    int wave = tid >> 6, lane = tid & 63;
    if (lane == 63) wtot[wave] = inc;
    __syncthreads();
    int woff = 0;
    for (int w = 0; w < wave; ++w) woff += wtot[w];
    if (tid < nblk) blk_off[tid] = woff + inc - v;
    if (tid == 255) row_start[n] = woff + inc;   // grand total
}

__global__ __launch_bounds__(256) void k_scan3(int* __restrict__ row_start,
                                               const int* __restrict__ blk_off,
                                               int* __restrict__ cursor, int n) {
    int i = blockIdx.x * 256 + threadIdx.x;
    if (i < n) {
        int rs = row_start[i] + blk_off[blockIdx.x];
        row_start[i] = rs;
        cursor[i] = rs;
    }
}

// scatter edges into CSR slots: col = src node, wgt = dinv[src]*dinv[dst]
__global__ __launch_bounds__(256) void k_fill(const int* __restrict__ src,
                                              const int* __restrict__ dst,
                                              const float* __restrict__ dinv,
                                              int* __restrict__ cursor,
                                              int* __restrict__ col,
                                              float* __restrict__ wgt, int e) {
    int i = blockIdx.x * 256 + threadIdx.x;
    if (i < e) {
        int s = src[i], t = dst[i];
        int pos = atomicAdd(&cursor[t], 1);
        col[pos] = s;
        wgt[pos] = dinv[s] * dinv[t];
    }
}

// ---------------------------------------------------------------------------
// H = X @ W   (X: [n,128] fp32, W: [128,128] fp32, H: [n,128] bf16)
// block: 256 thr, tile 32 rows x 128 cols; K split in two 64-wide halves so
// LDS = 32 KB (W half) + 8 KB (X half-tile) = 40 KB.
__global__ __launch_bounds__(256) void k_gemm(const float* __restrict__ X,
                                              const float* __restrict__ W,
                                              unsigned short* __restrict__ H, int n) {
    __shared__ float ws[64 * DIM];   // 32 KB
    __shared__ float xs[32 * 64];    // 8 KB
    int t = threadIdx.x;
    int r0b = blockIdx.x * 32;
    int ty = t >> 5;          // 0..7 -> 4-row group
    int tx = t & 31;          // 0..31 -> 4-col group
    int r0 = ty * 4;
    int c0 = tx * 4;
    float acc[4][4] = {};

    const float4* W4 = (const float4*)W;
    const float4* X4 = (const float4*)X;
    float4* ws4 = (float4*)ws;
    float4* xs4 = (float4*)xs;

    for (int kh = 0; kh < 2; ++kh) {
        if (kh) __syncthreads();   // finish compute on half 0 before overwrite
#pragma unroll
        for (int i = 0; i < 8; ++i) {
            int idx = t + 256 * i;                 // 0..2047 float4s = 32 KB
            ws4[idx] = W4[kh * 2048 + idx];
        }
#pragma unroll
        for (int i = 0; i < 2; ++i) {
            int f = t + 256 * i;                   // 0..511 float4s = 8 KB
            int row = f >> 4;                      // 0..31
            int cg  = f & 15;                      // float4 within 64-col half
            float4 v = make_float4(0.f, 0.f, 0.f, 0.f);
            if (r0b + row < n) v = X4[(size_t)(r0b + row) * 32 + kh * 16 + cg];
            xs4[f] = v;
        }
        __syncthreads();
#pragma unroll 4
        for (int k = 0; k < 64; ++k) {
            float4 b = *(const float4*)&ws[k * DIM + c0];
            float a0 = xs[(r0 + 0) * 64 + k];
            float a1 = xs[(r0 + 1) * 64 + k];
            float a2 = xs[(r0 + 2) * 64 + k];
            float a3 = xs[(r0 + 3) * 64 + k];
            acc[0][0] += a0 * b.x; acc[0][1] += a0 * b.y; acc[0][2] += a0 * b.z; acc[0][3] += a0 * b.w;
            acc[1][0] += a1 * b.x; acc[1][1] += a1 * b.y; acc[1][2] += a1 * b.z; acc[1][3] += a1 * b.w;
            acc[2][0] += a2 * b.x; acc[2][1] += a2 * b.y; acc[2][2] += a2 * b.z; acc[2][3] += a2 * b.w;
            acc[3][0] += a3 * b.x; acc[3][1] += a3 * b.y; acc[3][2] += a3 * b.z; acc[3][3] += a3 * b.w;
        }
    }
#pragma unroll
    for (int i = 0; i < 4; ++i) {
        int row = r0b + r0 + i;
        if (row < n) {
            uint2 pv;
            pv.x = pack2(acc[i][0], acc[i][1]);
            pv.y = pack2(acc[i][2], acc[i][3]);
            *(uint2*)&H[(size_t)row * DIM + c0] = pv;   // byte off = (row*128+c0)*2, 8B-aligned
        }
    }
}

// ---------------------------------------------------------------------------
// out[i,:] = sum_{j in in-edges(i)} H[col[j],:]*wgt[j] + H[i,:]*dinv[i]^2 + bias
// H is bf16. One node per 128 threads (2 nodes / 256-thr block); 8-edge unroll.
__global__ __launch_bounds__(256) void k_agg(const unsigned short* __restrict__ H,
                                             const float* __restrict__ bias,
                                             const float* __restrict__ dinv,
                                             const int* __restrict__ row_start,
                                             const int* __restrict__ col,
                                             const float* __restrict__ wgt,
                                             float* __restrict__ out, int n, int e) {
    int node = blockIdx.x * 2 + (threadIdx.x >> 7);
    int d = threadIdx.x & 127;
    if (node >= n) return;
    float di = dinv[node];
    float acc = bf2f(H[(size_t)node * DIM + d]) * (di * di) + bias[d];
    int jb = row_start[node], je = row_start[node + 1];
    jb = min(max(jb, 0), e);          // clamp: garbage can't cause hang/OOB
    je = min(max(je, jb), e);
    int j = jb;
    for (; j + 8 <= je; j += 8) {
        int c[8]; float w[8]; float h[8];
#pragma unroll
        for (int u = 0; u < 8; ++u) { c[u] = col[j + u]; w[u] = wgt[j + u]; }
#pragma unroll
        for (int u = 0; u < 8; ++u) h[u] = bf2f(H[(size_t)c[u] * DIM + d]);
#pragma unroll
        for (int u = 0; u < 8; ++u) acc += h[u] * w[u];
    }
    for (; j < je; ++j) acc += bf2f(H[(size_t)col[j] * DIM + d]) * wgt[j];
    out[(size_t)node * DIM + d] = acc;
}

// ---------------------------------------------------------------------------
// column sums + sums of squares -> sums[0..127]=sum, sums[128..255]=sumsq
__global__ __launch_bounds__(256) void k_stats(const float* __restrict__ V,
                                               float* __restrict__ sums, int n) {
    int d = threadIdx.x & 127;
    int half = threadIdx.x >> 7;
    int r0 = blockIdx.x * 256;
    int r1 = min(r0 + 256, n);
    float s = 0.f, q = 0.f;
    for (int r = r0 + half; r < r1; r += 2) {
        float v = V[(size_t)r * DIM + d];
        s += v; q += v * v;
    }
    __shared__ float ls[256], lq[256];
    ls[threadIdx.x] = s; lq[threadIdx.x] = q;
    __syncthreads();
    if (half == 0) {
        atomicAdd(&sums[d], s + ls[threadIdx.x + 128]);
        atomicAdd(&sums[128 + d], q + lq[threadIdx.x + 128]);
    }
}

// BN (training-mode batch stats) + ReLU, in place
__global__ __launch_bounds__(256) void k_bn_relu(float* __restrict__ V,
                                                 const float* __restrict__ sums,
                                                 const float* __restrict__ gamma,
                                                 const float* __restrict__ beta,
                                                 int n, float invN) {
    int idx = blockIdx.x * 256 + threadIdx.x;
    if (idx >= n * DIM) return;
    int d = idx & 127;
    float mu = sums[d] * invN;
    float var = sums[128 + d] * invN - mu * mu;
    float inv = rsqrtf(var + BN_EPS);
    float scale = gamma[d] * inv;
    float shift = beta[d] - mu * scale;
    float v = V[idx] * scale + shift;
    V[idx] = fmaxf(v, 0.f);
}

// BN + residual + ReLU -> out (element-wise; safe when V == out)
__global__ __launch_bounds__(256) void k_bn_res_relu(const float* __restrict__ V,
                                                     const float* __restrict__ X,
                                                     const float* __restrict__ sums,
                                                     const float* __restrict__ gamma,
                                                     const float* __restrict__ beta,
                                                     float* __restrict__ out,
                                                     int n, float invN) {
    int idx = blockIdx.x * 256 + threadIdx.x;
    if (idx >= n * DIM) return;
    int d = idx & 127;
    float mu = sums[d] * invN;
    float var = sums[128 + d] * invN - mu * mu;
    float inv = rsqrtf(var + BN_EPS);
    float scale = gamma[d] * inv;
    float shift = beta[d] - mu * scale;
    float v = V[idx] * scale + shift + X[idx];
    out[idx] = fmaxf(v, 0.f);
}

// ---------------------------------------------------------------------------
extern "C" void kernel_launch(void* const* d_in, const int* in_sizes, int n_in,
                              void* d_out, int out_size, void* d_ws, size_t ws_size,
                              hipStream_t stream) {
    const float* x      = (const float*)d_in[0];
    const int*   ei     = (const int*)d_in[1];
    const float* W1     = (const float*)d_in[2];
    const float* b1     = (const float*)d_in[3];
    const float* gamma1 = (const float*)d_in[4];
    const float* beta1  = (const float*)d_in[5];
    const float* W2     = (const float*)d_in[6];
    const float* b2     = (const float*)d_in[7];
    const float* gamma2 = (const float*)d_in[8];
    const float* beta2  = (const float*)d_in[9];
    float* out = (float*)d_out;

    int n = in_sizes[0] / DIM;   // 50000
    int e = in_sizes[1] / 2;     // 800000
    const int* srcIdx = ei;       // edge_index[0,:]
    const int* dstIdx = ei + e;   // edge_index[1,:]

    int gN    = (n + 255) / 256;
    int gE    = (e + 255) / 256;
    int gRows = (n + 31) / 32;
    int gNode = (n + 1) / 2;
    int gElem = (n * DIM + 255) / 256;
    float invN = 1.0f / (float)n;

    char* ws = (char*)d_ws;
    size_t off = 0;
    auto alloc = [&](size_t bytes) -> void* {
        void* p = ws + off;
        off += (bytes + 255) & ~(size_t)255;
        return p;
    };
    int*   deg_cnt   = (int*)  alloc((size_t)n * 4);
    float* dinv      = (float*)alloc((size_t)n * 4);
    int*   row_start = (int*)  alloc((size_t)(n + 1) * 4);
    int*   cursor    = (int*)  alloc((size_t)n * 4);
    int*   blk_sum   = (int*)  alloc((size_t)gN * 4);
    int*   blk_off   = (int*)  alloc((size_t)gN * 4);
    int*   col       = (int*)  alloc((size_t)e * 4);
    float* wgt       = (float*)alloc((size_t)e * 4);
    unsigned short* Hb = (unsigned short*)alloc((size_t)n * DIM * 2);  // bf16 H
    float* stats     = (float*)alloc(512 * 4);   // [stats1 | stats2]
    float* stats1 = stats;
    float* stats2 = stats + 256;
    // d_out doubles as the fp32 N x D buffer (fully overwritten at the end,
    // final BN pass is element-wise in-place-safe).
    float* bufB = out;

    // workspace guard: fail cleanly (wrong output) instead of corrupting memory
    if (off > ws_size || gN > 256) return;

    // graph preprocessing: degrees -> dinv -> CSR
    k_init<<<gN, 256, 0, stream>>>(deg_cnt, stats, n);
    k_deg<<<gE, 256, 0, stream>>>(dstIdx, deg_cnt, e);
    k_dinv<<<gN, 256, 0, stream>>>(deg_cnt, dinv, n);
    k_scan1<<<gN, 256, 0, stream>>>(deg_cnt, row_start, blk_sum, n);
    k_scan2<<<1, 256, 0, stream>>>(blk_sum, blk_off, row_start, gN, n);
    k_scan3<<<gN, 256, 0, stream>>>(row_start, blk_off, cursor, n);
    k_fill<<<gE, 256, 0, stream>>>(srcIdx, dstIdx, dinv, cursor, col, wgt, e);

    // conv1 + BN + ReLU
    k_gemm<<<gRows, 256, 0, stream>>>(x, W1, Hb, n);
    k_agg<<<gNode, 256, 0, stream>>>(Hb, b1, dinv, row_start, col, wgt, bufB, n, e);
    k_stats<<<gN, 256, 0, stream>>>(bufB, stats1, n);
    k_bn_relu<<<gElem, 256, 0, stream>>>(bufB, stats1, gamma1, beta1, n, invN);

    // conv2 + BN + residual + ReLU
    k_gemm<<<gRows, 256, 0, stream>>>(bufB, W2, Hb, n);
    k_agg<<<gNode, 256, 0, stream>>>(Hb, b2, dinv, row_start, col, wgt, bufB, n, e);
    k_stats<<<gN, 256, 0, stream>>>(bufB, stats2, n);
    k_bn_res_relu<<<gElem, 256, 0, stream>>>(bufB, x, stats2, gamma2, beta2, out, n, invN);
}

// Round 9
// 419.099 us; speedup vs baseline: 1.2312x; 1.1021x over previous
//
#include <hip/hip_runtime.h>

#define DIM 128
#define BN_EPS 1e-5f

// ---- bf16 helpers ----
__device__ __forceinline__ float bflo(unsigned int h) {
    return __uint_as_float(h << 16);
}
__device__ __forceinline__ float bfhi(unsigned int h) {
    return __uint_as_float(h & 0xffff0000u);
}
__device__ __forceinline__ unsigned int f2bf(float f) {
    unsigned int u = __float_as_uint(f);
    return (u + 0x7fffu + ((u >> 16) & 1u)) >> 16;   // round-to-nearest-even
}
__device__ __forceinline__ unsigned int pack2(float a, float b) {
    return f2bf(a) | (f2bf(b) << 16);
}

// ---------------------------------------------------------------------------
// init: zero degree counters and BN stats accumulators
__global__ __launch_bounds__(256) void k_init(int* __restrict__ deg_cnt,
                                              float* __restrict__ stats, int n) {
    int i = blockIdx.x * 256 + threadIdx.x;
    if (i < n) deg_cnt[i] = 0;
    if (i < 512) stats[i] = 0.0f;
}

// in-degree histogram over dst
__global__ __launch_bounds__(256) void k_deg(const int* __restrict__ dst,
                                             int* __restrict__ deg_cnt, int e) {
    int i = blockIdx.x * 256 + threadIdx.x;
    if (i < e) atomicAdd(&deg_cnt[dst[i]], 1);
}

// dinv[i] = rsqrt(deg_cnt[i] + 1)   (self-loop adds 1)
__global__ __launch_bounds__(256) void k_dinv(const int* __restrict__ deg_cnt,
                                              float* __restrict__ dinv, int n) {
    int i = blockIdx.x * 256 + threadIdx.x;
    if (i < n) dinv[i] = rsqrtf((float)deg_cnt[i] + 1.0f);
}

// ---------------------------------------------------------------------------
// hierarchical exclusive scan (all 256-thread blocks)
__device__ __forceinline__ int wave_scan_incl(int v) {
    int lane = threadIdx.x & 63;
#pragma unroll
    for (int off = 1; off < 64; off <<= 1) {
        int t = __shfl_up(v, off, 64);
        if (lane >= off) v += t;
    }
    return v;
}

__global__ __launch_bounds__(256) void k_scan1(const int* __restrict__ deg_cnt,
                                               int* __restrict__ row_start,
                                               int* __restrict__ blk_sum, int n) {
    int tid = threadIdx.x;
    int i = blockIdx.x * 256 + tid;
    int v = (i < n) ? deg_cnt[i] : 0;
    int inc = wave_scan_incl(v);
    __shared__ int wtot[4];
    int wave = tid >> 6, lane = tid & 63;
    if (lane == 63) wtot[wave] = inc;
    __syncthreads();
    int woff = 0;
    for (int w = 0; w < wave; ++w) woff += wtot[w];
    int excl = woff + inc - v;
    if (i < n) row_start[i] = excl;
    if (tid == 255) blk_sum[blockIdx.x] = woff + inc;
}

__global__ __launch_bounds__(256) void k_scan2(const int* __restrict__ blk_sum,
                                               int* __restrict__ blk_off,
                                               int* __restrict__ row_start,
                                               int nblk, int n) {
    int tid = threadIdx.x;
    int v = (tid < nblk) ? blk_sum[tid] : 0;
    int inc = wave_scan_incl(v);
    __shared__ int wtot[4];
    int wave = tid >> 6, lane = tid & 63;
    if (lane == 63) wtot[wave] = inc;
    __syncthreads();
    int woff = 0;
    for (int w = 0; w < wave; ++w) woff += wtot[w];
    if (tid < nblk) blk_off[tid] = woff + inc - v;
    if (tid == 255) row_start[n] = woff + inc;   // grand total
}

__global__ __launch_bounds__(256) void k_scan3(int* __restrict__ row_start,
                                               const int* __restrict__ blk_off,
                                               int* __restrict__ cursor, int n) {
    int i = blockIdx.x * 256 + threadIdx.x;
    if (i < n) {
        int rs = row_start[i] + blk_off[blockIdx.x];
        row_start[i] = rs;
        cursor[i] = rs;
    }
}

// scatter edges into CSR slots: col = src node, wgt = dinv[src]*dinv[dst]
__global__ __launch_bounds__(256) void k_fill(const int* __restrict__ src,
                                              const int* __restrict__ dst,
                                              const float* __restrict__ dinv,
                                              int* __restrict__ cursor,
                                              int* __restrict__ col,
                                              float* __restrict__ wgt, int e) {
    int i = blockIdx.x * 256 + threadIdx.x;
    if (i < e) {
        int s = src[i], t = dst[i];
        int pos = atomicAdd(&cursor[t], 1);
        col[pos] = s;
        wgt[pos] = dinv[s] * dinv[t];
    }
}

// ---------------------------------------------------------------------------
// H = X @ W   (X: [n,128] fp32, W: [128,128] fp32, H: [n,128] bf16)
// block: 256 thr, tile 32 rows x 128 cols; K split in two 64-wide halves so
// LDS = 32 KB (W half) + 8 KB (X half-tile) = 40 KB.
__global__ __launch_bounds__(256) void k_gemm(const float* __restrict__ X,
                                              const float* __restrict__ W,
                                              unsigned short* __restrict__ H, int n) {
    __shared__ float ws[64 * DIM];   // 32 KB
    __shared__ float xs[32 * 64];    // 8 KB
    int t = threadIdx.x;
    int r0b = blockIdx.x * 32;
    int ty = t >> 5;          // 0..7 -> 4-row group
    int tx = t & 31;          // 0..31 -> 4-col group
    int r0 = ty * 4;
    int c0 = tx * 4;
    float acc[4][4] = {};

    const float4* W4 = (const float4*)W;
    const float4* X4 = (const float4*)X;
    float4* ws4 = (float4*)ws;
    float4* xs4 = (float4*)xs;

    for (int kh = 0; kh < 2; ++kh) {
        if (kh) __syncthreads();   // finish compute on half 0 before overwrite
#pragma unroll
        for (int i = 0; i < 8; ++i) {
            int idx = t + 256 * i;                 // 0..2047 float4s = 32 KB
            ws4[idx] = W4[kh * 2048 + idx];
        }
#pragma unroll
        for (int i = 0; i < 2; ++i) {
            int f = t + 256 * i;                   // 0..511 float4s = 8 KB
            int row = f >> 4;                      // 0..31
            int cg  = f & 15;                      // float4 within 64-col half
            float4 v = make_float4(0.f, 0.f, 0.f, 0.f);
            if (r0b + row < n) v = X4[(size_t)(r0b + row) * 32 + kh * 16 + cg];
            xs4[f] = v;
        }
        __syncthreads();
#pragma unroll 4
        for (int k = 0; k < 64; ++k) {
            float4 b = *(const float4*)&ws[k * DIM + c0];
            float a0 = xs[(r0 + 0) * 64 + k];
            float a1 = xs[(r0 + 1) * 64 + k];
            float a2 = xs[(r0 + 2) * 64 + k];
            float a3 = xs[(r0 + 3) * 64 + k];
            acc[0][0] += a0 * b.x; acc[0][1] += a0 * b.y; acc[0][2] += a0 * b.z; acc[0][3] += a0 * b.w;
            acc[1][0] += a1 * b.x; acc[1][1] += a1 * b.y; acc[1][2] += a1 * b.z; acc[1][3] += a1 * b.w;
            acc[2][0] += a2 * b.x; acc[2][1] += a2 * b.y; acc[2][2] += a2 * b.z; acc[2][3] += a2 * b.w;
            acc[3][0] += a3 * b.x; acc[3][1] += a3 * b.y; acc[3][2] += a3 * b.z; acc[3][3] += a3 * b.w;
        }
    }
#pragma unroll
    for (int i = 0; i < 4; ++i) {
        int row = r0b + r0 + i;
        if (row < n) {
            uint2 pv;
            pv.x = pack2(acc[i][0], acc[i][1]);
            pv.y = pack2(acc[i][2], acc[i][3]);
            *(uint2*)&H[(size_t)row * DIM + c0] = pv;   // byte off = (row*128+c0)*2, 8B-aligned
        }
    }
}

// ---------------------------------------------------------------------------
// out[i,:] = sum_{j in in-edges(i)} H[col[j],:]*wgt[j] + H[i,:]*dinv[i]^2 + bias
// H is bf16. ONE WAVE per node (4 nodes / 256-thr block); lane owns channels
// 2*lane, 2*lane+1 via one packed uint load per edge; 8-edge unroll.
__global__ __launch_bounds__(256) void k_agg(const unsigned int* __restrict__ Hp,  // bf16 pairs
                                             const float* __restrict__ bias,
                                             const float* __restrict__ dinv,
                                             const int* __restrict__ row_start,
                                             const int* __restrict__ col,
                                             const float* __restrict__ wgt,
                                             float* __restrict__ out, int n, int e) {
    int node = blockIdx.x * 4 + (threadIdx.x >> 6);
    int lane = threadIdx.x & 63;
    if (node >= n) return;
    float di = dinv[node];
    float dsq = di * di;
    float b0 = bias[2 * lane];
    float b1 = bias[2 * lane + 1];
    unsigned int hs = Hp[(size_t)node * 64 + lane];
    float a0 = bflo(hs) * dsq + b0;
    float a1 = bfhi(hs) * dsq + b1;
    int jb = row_start[node], je = row_start[node + 1];
    jb = min(max(jb, 0), e);          // clamp: garbage can't cause hang/OOB
    je = min(max(je, jb), e);
    int j = jb;
    for (; j + 8 <= je; j += 8) {
        int c[8]; float w[8]; unsigned int h[8];
#pragma unroll
        for (int u = 0; u < 8; ++u) { c[u] = col[j + u]; w[u] = wgt[j + u]; }
#pragma unroll
        for (int u = 0; u < 8; ++u) h[u] = Hp[(size_t)c[u] * 64 + lane];
#pragma unroll
        for (int u = 0; u < 8; ++u) {
            a0 += bflo(h[u]) * w[u];
            a1 += bfhi(h[u]) * w[u];
        }
    }
    for (; j < je; ++j) {
        float w = wgt[j];
        unsigned int h = Hp[(size_t)col[j] * 64 + lane];
        a0 += bflo(h) * w;
        a1 += bfhi(h) * w;
    }
    out[(size_t)node * DIM + 2 * lane]     = a0;
    out[(size_t)node * DIM + 2 * lane + 1] = a1;
}

// ---------------------------------------------------------------------------
// column sums + sums of squares -> sums[0..127]=sum, sums[128..255]=sumsq
__global__ __launch_bounds__(256) void k_stats(const float* __restrict__ V,
                                               float* __restrict__ sums, int n) {
    int d = threadIdx.x & 127;
    int half = threadIdx.x >> 7;
    int r0 = blockIdx.x * 256;
    int r1 = min(r0 + 256, n);
    float s = 0.f, q = 0.f;
    for (int r = r0 + half; r < r1; r += 2) {
        float v = V[(size_t)r * DIM + d];
        s += v; q += v * v;
    }
    __shared__ float ls[256], lq[256];
    ls[threadIdx.x] = s; lq[threadIdx.x] = q;
    __syncthreads();
    if (half == 0) {
        atomicAdd(&sums[d], s + ls[threadIdx.x + 128]);
        atomicAdd(&sums[128 + d], q + lq[threadIdx.x + 128]);
    }
}

// BN (training-mode batch stats) + ReLU, in place
__global__ __launch_bounds__(256) void k_bn_relu(float* __restrict__ V,
                                                 const float* __restrict__ sums,
                                                 const float* __restrict__ gamma,
                                                 const float* __restrict__ beta,
                                                 int n, float invN) {
    int idx = blockIdx.x * 256 + threadIdx.x;
    if (idx >= n * DIM) return;
    int d = idx & 127;
    float mu = sums[d] * invN;
    float var = sums[128 + d] * invN - mu * mu;
    float inv = rsqrtf(var + BN_EPS);
    float scale = gamma[d] * inv;
    float shift = beta[d] - mu * scale;
    float v = V[idx] * scale + shift;
    V[idx] = fmaxf(v, 0.f);
}

// BN + residual + ReLU -> out (element-wise; safe when V == out)
__global__ __launch_bounds__(256) void k_bn_res_relu(const float* __restrict__ V,
                                                     const float* __restrict__ X,
                                                     const float* __restrict__ sums,
                                                     const float* __restrict__ gamma,
                                                     const float* __restrict__ beta,
                                                     float* __restrict__ out,
                                                     int n, float invN) {
    int idx = blockIdx.x * 256 + threadIdx.x;
    if (idx >= n * DIM) return;
    int d = idx & 127;
    float mu = sums[d] * invN;
    float var = sums[128 + d] * invN - mu * mu;
    float inv = rsqrtf(var + BN_EPS);
    float scale = gamma[d] * inv;
    float shift = beta[d] - mu * scale;
    float v = V[idx] * scale + shift + X[idx];
    out[idx] = fmaxf(v, 0.f);
}

// ---------------------------------------------------------------------------
extern "C" void kernel_launch(void* const* d_in, const int* in_sizes, int n_in,
                              void* d_out, int out_size, void* d_ws, size_t ws_size,
                              hipStream_t stream) {
    const float* x      = (const float*)d_in[0];
    const int*   ei     = (const int*)d_in[1];
    const float* W1     = (const float*)d_in[2];
    const float* b1     = (const float*)d_in[3];
    const float* gamma1 = (const float*)d_in[4];
    const float* beta1  = (const float*)d_in[5];
    const float* W2     = (const float*)d_in[6];
    const float* b2     = (const float*)d_in[7];
    const float* gamma2 = (const float*)d_in[8];
    const float* beta2  = (const float*)d_in[9];
    float* out = (float*)d_out;

    int n = in_sizes[0] / DIM;   // 50000
    int e = in_sizes[1] / 2;     // 800000
    const int* srcIdx = ei;       // edge_index[0,:]
    const int* dstIdx = ei + e;   // edge_index[1,:]

    int gN    = (n + 255) / 256;
    int gE    = (e + 255) / 256;
    int gRows = (n + 31) / 32;
    int gNode = (n + 3) / 4;
    int gElem = (n * DIM + 255) / 256;
    float invN = 1.0f / (float)n;

    char* ws = (char*)d_ws;
    size_t off = 0;
    auto alloc = [&](size_t bytes) -> void* {
        void* p = ws + off;
        off += (bytes + 255) & ~(size_t)255;
        return p;
    };
    int*   deg_cnt   = (int*)  alloc((size_t)n * 4);
    float* dinv      = (float*)alloc((size_t)n * 4);
    int*   row_start = (int*)  alloc((size_t)(n + 1) * 4);
    int*   cursor    = (int*)  alloc((size_t)n * 4);
    int*   blk_sum   = (int*)  alloc((size_t)gN * 4);
    int*   blk_off   = (int*)  alloc((size_t)gN * 4);
    int*   col       = (int*)  alloc((size_t)e * 4);
    float* wgt       = (float*)alloc((size_t)e * 4);
    unsigned short* Hb = (unsigned short*)alloc((size_t)n * DIM * 2);  // bf16 H
    float* stats     = (float*)alloc(512 * 4);   // [stats1 | stats2]
    float* stats1 = stats;
    float* stats2 = stats + 256;
    // d_out doubles as the fp32 N x D buffer (fully overwritten at the end,
    // final BN pass is element-wise in-place-safe).
    float* bufB = out;

    // workspace guard: fail cleanly (wrong output) instead of corrupting memory
    if (off > ws_size || gN > 256) return;

    // graph preprocessing: degrees -> dinv -> CSR
    k_init<<<gN, 256, 0, stream>>>(deg_cnt, stats, n);
    k_deg<<<gE, 256, 0, stream>>>(dstIdx, deg_cnt, e);
    k_dinv<<<gN, 256, 0, stream>>>(deg_cnt, dinv, n);
    k_scan1<<<gN, 256, 0, stream>>>(deg_cnt, row_start, blk_sum, n);
    k_scan2<<<1, 256, 0, stream>>>(blk_sum, blk_off, row_start, gN, n);
    k_scan3<<<gN, 256, 0, stream>>>(row_start, blk_off, cursor, n);
    k_fill<<<gE, 256, 0, stream>>>(srcIdx, dstIdx, dinv, cursor, col, wgt, e);

    // conv1 + BN + ReLU
    k_gemm<<<gRows, 256, 0, stream>>>(x, W1, Hb, n);
    k_agg<<<gNode, 256, 0, stream>>>((const unsigned int*)Hb, b1, dinv, row_start, col, wgt, bufB, n, e);
    k_stats<<<gN, 256, 0, stream>>>(bufB, stats1, n);
    k_bn_relu<<<gElem, 256, 0, stream>>>(bufB, stats1, gamma1, beta1, n, invN);

    // conv2 + BN + residual + ReLU
    k_gemm<<<gRows, 256, 0, stream>>>(bufB, W2, Hb, n);
    k_agg<<<gNode, 256, 0, stream>>>((const unsigned int*)Hb, b2, dinv, row_start, col, wgt, bufB, n, e);
    k_stats<<<gN, 256, 0, stream>>>(bufB, stats2, n);
    k_bn_res_relu<<<gElem, 256, 0, stream>>>(bufB, x, stats2, gamma2, beta2, out, n, invN);
}

// Round 10
// 410.307 us; speedup vs baseline: 1.2576x; 1.0214x over previous
//
#include <hip/hip_runtime.h>

#define DIM 128
#define BN_EPS 1e-5f

// ---- bf16 helpers ----
__device__ __forceinline__ float bflo(unsigned int h) {
    return __uint_as_float(h << 16);
}
__device__ __forceinline__ float bfhi(unsigned int h) {
    return __uint_as_float(h & 0xffff0000u);
}
__device__ __forceinline__ unsigned int f2bf(float f) {
    unsigned int u = __float_as_uint(f);
    return (u + 0x7fffu + ((u >> 16) & 1u)) >> 16;   // round-to-nearest-even
}
__device__ __forceinline__ unsigned int pack2(float a, float b) {
    return f2bf(a) | (f2bf(b) << 16);
}

// ---------------------------------------------------------------------------
// init: zero degree counters and BN stats accumulators
__global__ __launch_bounds__(256) void k_init(int* __restrict__ deg_cnt,
                                              float* __restrict__ stats, int n) {
    int i = blockIdx.x * 256 + threadIdx.x;
    if (i < n) deg_cnt[i] = 0;
    if (i < 512) stats[i] = 0.0f;
}

// in-degree histogram over dst
__global__ __launch_bounds__(256) void k_deg(const int* __restrict__ dst,
                                             int* __restrict__ deg_cnt, int e) {
    int i = blockIdx.x * 256 + threadIdx.x;
    if (i < e) atomicAdd(&deg_cnt[dst[i]], 1);
}

// dinv[i] = rsqrt(deg_cnt[i] + 1)   (self-loop adds 1)
__global__ __launch_bounds__(256) void k_dinv(const int* __restrict__ deg_cnt,
                                              float* __restrict__ dinv, int n) {
    int i = blockIdx.x * 256 + threadIdx.x;
    if (i < n) dinv[i] = rsqrtf((float)deg_cnt[i] + 1.0f);
}

// ---------------------------------------------------------------------------
// hierarchical exclusive scan (all 256-thread blocks)
__device__ __forceinline__ int wave_scan_incl(int v) {
    int lane = threadIdx.x & 63;
#pragma unroll
    for (int off = 1; off < 64; off <<= 1) {
        int t = __shfl_up(v, off, 64);
        if (lane >= off) v += t;
    }
    return v;
}

__global__ __launch_bounds__(256) void k_scan1(const int* __restrict__ deg_cnt,
                                               int* __restrict__ row_start,
                                               int* __restrict__ blk_sum, int n) {
    int tid = threadIdx.x;
    int i = blockIdx.x * 256 + tid;
    int v = (i < n) ? deg_cnt[i] : 0;
    int inc = wave_scan_incl(v);
    __shared__ int wtot[4];
    int wave = tid >> 6, lane = tid & 63;
    if (lane == 63) wtot[wave] = inc;
    __syncthreads();
    int woff = 0;
    for (int w = 0; w < wave; ++w) woff += wtot[w];
    int excl = woff + inc - v;
    if (i < n) row_start[i] = excl;
    if (tid == 255) blk_sum[blockIdx.x] = woff + inc;
}

__global__ __launch_bounds__(256) void k_scan2(const int* __restrict__ blk_sum,
                                               int* __restrict__ blk_off,
                                               int* __restrict__ row_start,
                                               int nblk, int n) {
    int tid = threadIdx.x;
    int v = (tid < nblk) ? blk_sum[tid] : 0;
    int inc = wave_scan_incl(v);
    __shared__ int wtot[4];
    int wave = tid >> 6, lane = tid & 63;
    if (lane == 63) wtot[wave] = inc;
    __syncthreads();
    int woff = 0;
    for (int w = 0; w < wave; ++w) woff += wtot[w];
    if (tid < nblk) blk_off[tid] = woff + inc - v;
    if (tid == 255) row_start[n] = woff + inc;   // grand total
}

__global__ __launch_bounds__(256) void k_scan3(int* __restrict__ row_start,
                                               const int* __restrict__ blk_off,
                                               int* __restrict__ cursor, int n) {
    int i = blockIdx.x * 256 + threadIdx.x;
    if (i < n) {
        int rs = row_start[i] + blk_off[blockIdx.x];
        row_start[i] = rs;
        cursor[i] = rs;
    }
}

// scatter edges into CSR slots: edge = (src, bitcast(wgt)) — one 8B store
__global__ __launch_bounds__(256) void k_fill(const int* __restrict__ src,
                                              const int* __restrict__ dst,
                                              const float* __restrict__ dinv,
                                              int* __restrict__ cursor,
                                              int2* __restrict__ edge, int e) {
    int i = blockIdx.x * 256 + threadIdx.x;
    if (i < e) {
        int s = src[i], t = dst[i];
        int pos = atomicAdd(&cursor[t], 1);
        float w = dinv[s] * dinv[t];
        edge[pos] = make_int2(s, __float_as_int(w));
    }
}

// ---------------------------------------------------------------------------
// H = X @ W   (X: [n,128] fp32, W: [128,128] fp32, H: [n,128] bf16)
// block: 256 thr, tile 32 rows x 128 cols; K split in two 64-wide halves so
// LDS = 32 KB (W half) + 8 KB (X half-tile) = 40 KB.
__global__ __launch_bounds__(256) void k_gemm(const float* __restrict__ X,
                                              const float* __restrict__ W,
                                              unsigned short* __restrict__ H, int n) {
    __shared__ float ws[64 * DIM];   // 32 KB
    __shared__ float xs[32 * 64];    // 8 KB
    int t = threadIdx.x;
    int r0b = blockIdx.x * 32;
    int ty = t >> 5;          // 0..7 -> 4-row group
    int tx = t & 31;          // 0..31 -> 4-col group
    int r0 = ty * 4;
    int c0 = tx * 4;
    float acc[4][4] = {};

    const float4* W4 = (const float4*)W;
    const float4* X4 = (const float4*)X;
    float4* ws4 = (float4*)ws;
    float4* xs4 = (float4*)xs;

    for (int kh = 0; kh < 2; ++kh) {
        if (kh) __syncthreads();   // finish compute on half 0 before overwrite
#pragma unroll
        for (int i = 0; i < 8; ++i) {
            int idx = t + 256 * i;                 // 0..2047 float4s = 32 KB
            ws4[idx] = W4[kh * 2048 + idx];
        }
#pragma unroll
        for (int i = 0; i < 2; ++i) {
            int f = t + 256 * i;                   // 0..511 float4s = 8 KB
            int row = f >> 4;                      // 0..31
            int cg  = f & 15;                      // float4 within 64-col half
            float4 v = make_float4(0.f, 0.f, 0.f, 0.f);
            if (r0b + row < n) v = X4[(size_t)(r0b + row) * 32 + kh * 16 + cg];
            xs4[f] = v;
        }
        __syncthreads();
#pragma unroll 4
        for (int k = 0; k < 64; ++k) {
            float4 b = *(const float4*)&ws[k * DIM + c0];
            float a0 = xs[(r0 + 0) * 64 + k];
            float a1 = xs[(r0 + 1) * 64 + k];
            float a2 = xs[(r0 + 2) * 64 + k];
            float a3 = xs[(r0 + 3) * 64 + k];
            acc[0][0] += a0 * b.x; acc[0][1] += a0 * b.y; acc[0][2] += a0 * b.z; acc[0][3] += a0 * b.w;
            acc[1][0] += a1 * b.x; acc[1][1] += a1 * b.y; acc[1][2] += a1 * b.z; acc[1][3] += a1 * b.w;
            acc[2][0] += a2 * b.x; acc[2][1] += a2 * b.y; acc[2][2] += a2 * b.z; acc[2][3] += a2 * b.w;
            acc[3][0] += a3 * b.x; acc[3][1] += a3 * b.y; acc[3][2] += a3 * b.z; acc[3][3] += a3 * b.w;
        }
    }
#pragma unroll
    for (int i = 0; i < 4; ++i) {
        int row = r0b + r0 + i;
        if (row < n) {
            uint2 pv;
            pv.x = pack2(acc[i][0], acc[i][1]);
            pv.y = pack2(acc[i][2], acc[i][3]);
            *(uint2*)&H[(size_t)row * DIM + c0] = pv;   // byte off = (row*128+c0)*2, 8B-aligned
        }
    }
}

// ---------------------------------------------------------------------------
// out[i,:] = sum_{j in in-edges(i)} H[edge[j].x,:]*edge[j].w + H[i,:]*dinv[i]^2 + bias
// H is bf16. ONE WAVE per node (4 nodes / 256-thr block); lane owns channels
// 2*lane, 2*lane+1 via one packed uint load per edge; 8-edge unroll.
__global__ __launch_bounds__(256) void k_agg(const unsigned int* __restrict__ Hp,  // bf16 pairs
                                             const float* __restrict__ bias,
                                             const float* __restrict__ dinv,
                                             const int* __restrict__ row_start,
                                             const int2* __restrict__ edge,
                                             float* __restrict__ out, int n, int e) {
    int node = blockIdx.x * 4 + (threadIdx.x >> 6);
    int lane = threadIdx.x & 63;
    if (node >= n) return;
    float di = dinv[node];
    float dsq = di * di;
    float b0 = bias[2 * lane];
    float b1 = bias[2 * lane + 1];
    unsigned int hs = Hp[(size_t)node * 64 + lane];
    float a0 = bflo(hs) * dsq + b0;
    float a1 = bfhi(hs) * dsq + b1;
    int jb = row_start[node], je = row_start[node + 1];
    jb = min(max(jb, 0), e);          // clamp: garbage can't cause hang/OOB
    je = min(max(je, jb), e);
    int j = jb;
    for (; j + 8 <= je; j += 8) {
        int2 ed[8]; unsigned int h[8];
#pragma unroll
        for (int u = 0; u < 8; ++u) ed[u] = edge[j + u];
#pragma unroll
        for (int u = 0; u < 8; ++u) h[u] = Hp[(size_t)ed[u].x * 64 + lane];
#pragma unroll
        for (int u = 0; u < 8; ++u) {
            float w = __int_as_float(ed[u].y);
            a0 += bflo(h[u]) * w;
            a1 += bfhi(h[u]) * w;
        }
    }
    for (; j < je; ++j) {
        int2 ed = edge[j];
        float w = __int_as_float(ed.y);
        unsigned int h = Hp[(size_t)ed.x * 64 + lane];
        a0 += bflo(h) * w;
        a1 += bfhi(h) * w;
    }
    out[(size_t)node * DIM + 2 * lane]     = a0;
    out[(size_t)node * DIM + 2 * lane + 1] = a1;
}

// ---------------------------------------------------------------------------
// column sums + sums of squares -> sums[0..127]=sum, sums[128..255]=sumsq
__global__ __launch_bounds__(256) void k_stats(const float* __restrict__ V,
                                               float* __restrict__ sums, int n) {
    int d = threadIdx.x & 127;
    int half = threadIdx.x >> 7;
    int r0 = blockIdx.x * 256;
    int r1 = min(r0 + 256, n);
    float s = 0.f, q = 0.f;
    for (int r = r0 + half; r < r1; r += 2) {
        float v = V[(size_t)r * DIM + d];
        s += v; q += v * v;
    }
    __shared__ float ls[256], lq[256];
    ls[threadIdx.x] = s; lq[threadIdx.x] = q;
    __syncthreads();
    if (half == 0) {
        atomicAdd(&sums[d], s + ls[threadIdx.x + 128]);
        atomicAdd(&sums[128 + d], q + lq[threadIdx.x + 128]);
    }
}

// BN (training-mode batch stats) + ReLU, in place
__global__ __launch_bounds__(256) void k_bn_relu(float* __restrict__ V,
                                                 const float* __restrict__ sums,
                                                 const float* __restrict__ gamma,
                                                 const float* __restrict__ beta,
                                                 int n, float invN) {
    int idx = blockIdx.x * 256 + threadIdx.x;
    if (idx >= n * DIM) return;
    int d = idx & 127;
    float mu = sums[d] * invN;
    float var = sums[128 + d] * invN - mu * mu;
    float inv = rsqrtf(var + BN_EPS);
    float scale = gamma[d] * inv;
    float shift = beta[d] - mu * scale;
    float v = V[idx] * scale + shift;
    V[idx] = fmaxf(v, 0.f);
}

// BN + residual + ReLU -> out (element-wise; safe when V == out)
__global__ __launch_bounds__(256) void k_bn_res_relu(const float* __restrict__ V,
                                                     const float* __restrict__ X,
                                                     const float* __restrict__ sums,
                                                     const float* __restrict__ gamma,
                                                     const float* __restrict__ beta,
                                                     float* __restrict__ out,
                                                     int n, float invN) {
    int idx = blockIdx.x * 256 + threadIdx.x;
    if (idx >= n * DIM) return;
    int d = idx & 127;
    float mu = sums[d] * invN;
    float var = sums[128 + d] * invN - mu * mu;
    float inv = rsqrtf(var + BN_EPS);
    float scale = gamma[d] * inv;
    float shift = beta[d] - mu * scale;
    float v = V[idx] * scale + shift + X[idx];
    out[idx] = fmaxf(v, 0.f);
}

// ---------------------------------------------------------------------------
extern "C" void kernel_launch(void* const* d_in, const int* in_sizes, int n_in,
                              void* d_out, int out_size, void* d_ws, size_t ws_size,
                              hipStream_t stream) {
    const float* x      = (const float*)d_in[0];
    const int*   ei     = (const int*)d_in[1];
    const float* W1     = (const float*)d_in[2];
    const float* b1     = (const float*)d_in[3];
    const float* gamma1 = (const float*)d_in[4];
    const float* beta1  = (const float*)d_in[5];
    const float* W2     = (const float*)d_in[6];
    const float* b2     = (const float*)d_in[7];
    const float* gamma2 = (const float*)d_in[8];
    const float* beta2  = (const float*)d_in[9];
    float* out = (float*)d_out;

    int n = in_sizes[0] / DIM;   // 50000
    int e = in_sizes[1] / 2;     // 800000
    const int* srcIdx = ei;       // edge_index[0,:]
    const int* dstIdx = ei + e;   // edge_index[1,:]

    int gN    = (n + 255) / 256;
    int gE    = (e + 255) / 256;
    int gRows = (n + 31) / 32;
    int gNode = (n + 3) / 4;
    int gElem = (n * DIM + 255) / 256;
    float invN = 1.0f / (float)n;

    char* ws = (char*)d_ws;
    size_t off = 0;
    auto alloc = [&](size_t bytes) -> void* {
        void* p = ws + off;
        off += (bytes + 255) & ~(size_t)255;
        return p;
    };
    int*   deg_cnt   = (int*)  alloc((size_t)n * 4);
    float* dinv      = (float*)alloc((size_t)n * 4);
    int*   row_start = (int*)  alloc((size_t)(n + 1) * 4);
    int*   cursor    = (int*)  alloc((size_t)n * 4);
    int*   blk_sum   = (int*)  alloc((size_t)gN * 4);
    int*   blk_off   = (int*)  alloc((size_t)gN * 4);
    int2*  edge      = (int2*) alloc((size_t)e * 8);              // (src, wgt)
    unsigned short* Hb = (unsigned short*)alloc((size_t)n * DIM * 2);  // bf16 H
    float* stats     = (float*)alloc(512 * 4);   // [stats1 | stats2]
    float* stats1 = stats;
    float* stats2 = stats + 256;
    // d_out doubles as the fp32 N x D buffer (fully overwritten at the end,
    // final BN pass is element-wise in-place-safe).
    float* bufB = out;

    // workspace guard: fail cleanly (wrong output) instead of corrupting memory
    if (off > ws_size || gN > 256) return;

    // graph preprocessing: degrees -> dinv -> CSR
    k_init<<<gN, 256, 0, stream>>>(deg_cnt, stats, n);
    k_deg<<<gE, 256, 0, stream>>>(dstIdx, deg_cnt, e);
    k_dinv<<<gN, 256, 0, stream>>>(deg_cnt, dinv, n);
    k_scan1<<<gN, 256, 0, stream>>>(deg_cnt, row_start, blk_sum, n);
    k_scan2<<<1, 256, 0, stream>>>(blk_sum, blk_off, row_start, gN, n);
    k_scan3<<<gN, 256, 0, stream>>>(row_start, blk_off, cursor, n);
    k_fill<<<gE, 256, 0, stream>>>(srcIdx, dstIdx, dinv, cursor, edge, e);

    // conv1 + BN + ReLU
    k_gemm<<<gRows, 256, 0, stream>>>(x, W1, Hb, n);
    k_agg<<<gNode, 256, 0, stream>>>((const unsigned int*)Hb, b1, dinv, row_start, edge, bufB, n, e);
    k_stats<<<gN, 256, 0, stream>>>(bufB, stats1, n);
    k_bn_relu<<<gElem, 256, 0, stream>>>(bufB, stats1, gamma1, beta1, n, invN);

    // conv2 + BN + residual + ReLU
    k_gemm<<<gRows, 256, 0, stream>>>(bufB, W2, Hb, n);
    k_agg<<<gNode, 256, 0, stream>>>((const unsigned int*)Hb, b2, dinv, row_start, edge, bufB, n, e);
    k_stats<<<gN, 256, 0, stream>>>(bufB, stats2, n);
    k_bn_res_relu<<<gElem, 256, 0, stream>>>(bufB, x, stats2, gamma2, beta2, out, n, invN);
}

// Round 11
// 405.733 us; speedup vs baseline: 1.2717x; 1.0113x over previous
//
#include <hip/hip_runtime.h>

#define DIM 128
#define BN_EPS 1e-5f

// ---- bf16 helpers ----
__device__ __forceinline__ float bflo(unsigned int h) {
    return __uint_as_float(h << 16);
}
__device__ __forceinline__ float bfhi(unsigned int h) {
    return __uint_as_float(h & 0xffff0000u);
}
__device__ __forceinline__ unsigned int f2bf(float f) {
    unsigned int u = __float_as_uint(f);
    return (u + 0x7fffu + ((u >> 16) & 1u)) >> 16;   // round-to-nearest-even
}
__device__ __forceinline__ unsigned int pack2(float a, float b) {
    return f2bf(a) | (f2bf(b) << 16);
}

// ---------------------------------------------------------------------------
// init: zero degree counters and BN stats accumulators
__global__ __launch_bounds__(256) void k_init(int* __restrict__ deg_cnt,
                                              float* __restrict__ stats, int n) {
    int i = blockIdx.x * 256 + threadIdx.x;
    if (i < n) deg_cnt[i] = 0;
    if (i < 512) stats[i] = 0.0f;
}

// in-degree histogram over dst
__global__ __launch_bounds__(256) void k_deg(const int* __restrict__ dst,
                                             int* __restrict__ deg_cnt, int e) {
    int i = blockIdx.x * 256 + threadIdx.x;
    if (i < e) atomicAdd(&deg_cnt[dst[i]], 1);
}

// dinv[i] = rsqrt(deg_cnt[i] + 1)   (self-loop adds 1)
__global__ __launch_bounds__(256) void k_dinv(const int* __restrict__ deg_cnt,
                                              float* __restrict__ dinv, int n) {
    int i = blockIdx.x * 256 + threadIdx.x;
    if (i < n) dinv[i] = rsqrtf((float)deg_cnt[i] + 1.0f);
}

// ---------------------------------------------------------------------------
// hierarchical exclusive scan (all 256-thread blocks)
__device__ __forceinline__ int wave_scan_incl(int v) {
    int lane = threadIdx.x & 63;
#pragma unroll
    for (int off = 1; off < 64; off <<= 1) {
        int t = __shfl_up(v, off, 64);
        if (lane >= off) v += t;
    }
    return v;
}

__global__ __launch_bounds__(256) void k_scan1(const int* __restrict__ deg_cnt,
                                               int* __restrict__ row_start,
                                               int* __restrict__ blk_sum, int n) {
    int tid = threadIdx.x;
    int i = blockIdx.x * 256 + tid;
    int v = (i < n) ? deg_cnt[i] : 0;
    int inc = wave_scan_incl(v);
    __shared__ int wtot[4];
    int wave = tid >> 6, lane = tid & 63;
    if (lane == 63) wtot[wave] = inc;
    __syncthreads();
    int woff = 0;
    for (int w = 0; w < wave; ++w) woff += wtot[w];
    int excl = woff + inc - v;
    if (i < n) row_start[i] = excl;
    if (tid == 255) blk_sum[blockIdx.x] = woff + inc;
}

__global__ __launch_bounds__(256) void k_scan2(const int* __restrict__ blk_sum,
                                               int* __restrict__ blk_off,
                                               int* __restrict__ row_start,
                                               int nblk, int n) {
    int tid = threadIdx.x;
    int v = (tid < nblk) ? blk_sum[tid] : 0;
    int inc = wave_scan_incl(v);
    __shared__ int wtot[4];
    int wave = tid >> 6, lane = tid & 63;
    if (lane == 63) wtot[wave] = inc;
    __syncthreads();
    int woff = 0;
    for (int w = 0; w < wave; ++w) woff += wtot[w];
    if (tid < nblk) blk_off[tid] = woff + inc - v;
    if (tid == 255) row_start[n] = woff + inc;   // grand total
}

__global__ __launch_bounds__(256) void k_scan3(int* __restrict__ row_start,
                                               const int* __restrict__ blk_off,
                                               int* __restrict__ cursor, int n) {
    int i = blockIdx.x * 256 + threadIdx.x;
    if (i < n) {
        int rs = row_start[i] + blk_off[blockIdx.x];
        row_start[i] = rs;
        cursor[i] = rs;
    }
}

// ---------------------------------------------------------------------------
// FUSED: blocks [0,fillBlocks) build the CSR edge array (memory-latency-bound
// scatter); blocks [fillBlocks, ...) compute H = X @ W1 (VALU-bound GEMM).
// The two are independent; co-residency hides the scatter latency behind the
// GEMM's compute. Branch is block-uniform.
__global__ __launch_bounds__(256) void k_fill_gemm(
        // fill args
        const int* __restrict__ src, const int* __restrict__ dst,
        const float* __restrict__ dinv, int* __restrict__ cursor,
        int2* __restrict__ edge, int e, int fillBlocks,
        // gemm args
        const float* __restrict__ X, const float* __restrict__ W,
        unsigned short* __restrict__ H, int n) {
    __shared__ float ws[64 * DIM];   // 32 KB (gemm branch only)
    __shared__ float xs[32 * 64];    // 8 KB

    if ((int)blockIdx.x < fillBlocks) {
        // ---- fill path ----
        int i = blockIdx.x * 256 + threadIdx.x;
        if (i < e) {
            int s = src[i], t = dst[i];
            int pos = atomicAdd(&cursor[t], 1);
            float w = dinv[s] * dinv[t];
            edge[pos] = make_int2(s, __float_as_int(w));
        }
        return;
    }

    // ---- gemm path ----
    int t = threadIdx.x;
    int r0b = ((int)blockIdx.x - fillBlocks) * 32;
    int ty = t >> 5;
    int tx = t & 31;
    int r0 = ty * 4;
    int c0 = tx * 4;
    float acc[4][4] = {};

    const float4* W4 = (const float4*)W;
    const float4* X4 = (const float4*)X;
    float4* ws4 = (float4*)ws;
    float4* xs4 = (float4*)xs;

    for (int kh = 0; kh < 2; ++kh) {
        if (kh) __syncthreads();
#pragma unroll
        for (int i = 0; i < 8; ++i) {
            int idx = t + 256 * i;
            ws4[idx] = W4[kh * 2048 + idx];
        }
#pragma unroll
        for (int i = 0; i < 2; ++i) {
            int f = t + 256 * i;
            int row = f >> 4;
            int cg  = f & 15;
            float4 v = make_float4(0.f, 0.f, 0.f, 0.f);
            if (r0b + row < n) v = X4[(size_t)(r0b + row) * 32 + kh * 16 + cg];
            xs4[f] = v;
        }
        __syncthreads();
#pragma unroll 4
        for (int k = 0; k < 64; ++k) {
            float4 b = *(const float4*)&ws[k * DIM + c0];
            float a0 = xs[(r0 + 0) * 64 + k];
            float a1 = xs[(r0 + 1) * 64 + k];
            float a2 = xs[(r0 + 2) * 64 + k];
            float a3 = xs[(r0 + 3) * 64 + k];
            acc[0][0] += a0 * b.x; acc[0][1] += a0 * b.y; acc[0][2] += a0 * b.z; acc[0][3] += a0 * b.w;
            acc[1][0] += a1 * b.x; acc[1][1] += a1 * b.y; acc[1][2] += a1 * b.z; acc[1][3] += a1 * b.w;
            acc[2][0] += a2 * b.x; acc[2][1] += a2 * b.y; acc[2][2] += a2 * b.z; acc[2][3] += a2 * b.w;
            acc[3][0] += a3 * b.x; acc[3][1] += a3 * b.y; acc[3][2] += a3 * b.z; acc[3][3] += a3 * b.w;
        }
    }
#pragma unroll
    for (int i = 0; i < 4; ++i) {
        int row = r0b + r0 + i;
        if (row < n) {
            uint2 pv;
            pv.x = pack2(acc[i][0], acc[i][1]);
            pv.y = pack2(acc[i][2], acc[i][3]);
            *(uint2*)&H[(size_t)row * DIM + c0] = pv;
        }
    }
}

// ---------------------------------------------------------------------------
// H = X @ W   (standalone, used for conv2)
__global__ __launch_bounds__(256) void k_gemm(const float* __restrict__ X,
                                              const float* __restrict__ W,
                                              unsigned short* __restrict__ H, int n) {
    __shared__ float ws[64 * DIM];   // 32 KB
    __shared__ float xs[32 * 64];    // 8 KB
    int t = threadIdx.x;
    int r0b = blockIdx.x * 32;
    int ty = t >> 5;
    int tx = t & 31;
    int r0 = ty * 4;
    int c0 = tx * 4;
    float acc[4][4] = {};

    const float4* W4 = (const float4*)W;
    const float4* X4 = (const float4*)X;
    float4* ws4 = (float4*)ws;
    float4* xs4 = (float4*)xs;

    for (int kh = 0; kh < 2; ++kh) {
        if (kh) __syncthreads();
#pragma unroll
        for (int i = 0; i < 8; ++i) {
            int idx = t + 256 * i;
            ws4[idx] = W4[kh * 2048 + idx];
        }
#pragma unroll
        for (int i = 0; i < 2; ++i) {
            int f = t + 256 * i;
            int row = f >> 4;
            int cg  = f & 15;
            float4 v = make_float4(0.f, 0.f, 0.f, 0.f);
            if (r0b + row < n) v = X4[(size_t)(r0b + row) * 32 + kh * 16 + cg];
            xs4[f] = v;
        }
        __syncthreads();
#pragma unroll 4
        for (int k = 0; k < 64; ++k) {
            float4 b = *(const float4*)&ws[k * DIM + c0];
            float a0 = xs[(r0 + 0) * 64 + k];
            float a1 = xs[(r0 + 1) * 64 + k];
            float a2 = xs[(r0 + 2) * 64 + k];
            float a3 = xs[(r0 + 3) * 64 + k];
            acc[0][0] += a0 * b.x; acc[0][1] += a0 * b.y; acc[0][2] += a0 * b.z; acc[0][3] += a0 * b.w;
            acc[1][0] += a1 * b.x; acc[1][1] += a1 * b.y; acc[1][2] += a1 * b.z; acc[1][3] += a1 * b.w;
            acc[2][0] += a2 * b.x; acc[2][1] += a2 * b.y; acc[2][2] += a2 * b.z; acc[2][3] += a2 * b.w;
            acc[3][0] += a3 * b.x; acc[3][1] += a3 * b.y; acc[3][2] += a3 * b.z; acc[3][3] += a3 * b.w;
        }
    }
#pragma unroll
    for (int i = 0; i < 4; ++i) {
        int row = r0b + r0 + i;
        if (row < n) {
            uint2 pv;
            pv.x = pack2(acc[i][0], acc[i][1]);
            pv.y = pack2(acc[i][2], acc[i][3]);
            *(uint2*)&H[(size_t)row * DIM + c0] = pv;
        }
    }
}

// ---------------------------------------------------------------------------
// out[i,:] = sum_{j in in-edges(i)} H[edge[j].x,:]*edge[j].w + H[i,:]*dinv[i]^2 + bias
// H is bf16. ONE WAVE per node (4 nodes / 256-thr block); lane owns channels
// 2*lane, 2*lane+1 via one packed uint load per edge; 8-edge unroll.
__global__ __launch_bounds__(256) void k_agg(const unsigned int* __restrict__ Hp,  // bf16 pairs
                                             const float* __restrict__ bias,
                                             const float* __restrict__ dinv,
                                             const int* __restrict__ row_start,
                                             const int2* __restrict__ edge,
                                             float* __restrict__ out, int n, int e) {
    int node = blockIdx.x * 4 + (threadIdx.x >> 6);
    int lane = threadIdx.x & 63;
    if (node >= n) return;
    float di = dinv[node];
    float dsq = di * di;
    float b0 = bias[2 * lane];
    float b1 = bias[2 * lane + 1];
    unsigned int hs = Hp[(size_t)node * 64 + lane];
    float a0 = bflo(hs) * dsq + b0;
    float a1 = bfhi(hs) * dsq + b1;
    int jb = row_start[node], je = row_start[node + 1];
    jb = min(max(jb, 0), e);          // clamp: garbage can't cause hang/OOB
    je = min(max(je, jb), e);
    int j = jb;
    for (; j + 8 <= je; j += 8) {
        int2 ed[8]; unsigned int h[8];
#pragma unroll
        for (int u = 0; u < 8; ++u) ed[u] = edge[j + u];
#pragma unroll
        for (int u = 0; u < 8; ++u) h[u] = Hp[(size_t)ed[u].x * 64 + lane];
#pragma unroll
        for (int u = 0; u < 8; ++u) {
            float w = __int_as_float(ed[u].y);
            a0 += bflo(h[u]) * w;
            a1 += bfhi(h[u]) * w;
        }
    }
    for (; j < je; ++j) {
        int2 ed = edge[j];
        float w = __int_as_float(ed.y);
        unsigned int h = Hp[(size_t)ed.x * 64 + lane];
        a0 += bflo(h) * w;
        a1 += bfhi(h) * w;
    }
    out[(size_t)node * DIM + 2 * lane]     = a0;
    out[(size_t)node * DIM + 2 * lane + 1] = a1;
}

// ---------------------------------------------------------------------------
// column sums + sums of squares -> sums[0..127]=sum, sums[128..255]=sumsq
__global__ __launch_bounds__(256) void k_stats(const float* __restrict__ V,
                                               float* __restrict__ sums, int n) {
    int d = threadIdx.x & 127;
    int half = threadIdx.x >> 7;
    int r0 = blockIdx.x * 256;
    int r1 = min(r0 + 256, n);
    float s = 0.f, q = 0.f;
    for (int r = r0 + half; r < r1; r += 2) {
        float v = V[(size_t)r * DIM + d];
        s += v; q += v * v;
    }
    __shared__ float ls[256], lq[256];
    ls[threadIdx.x] = s; lq[threadIdx.x] = q;
    __syncthreads();
    if (half == 0) {
        atomicAdd(&sums[d], s + ls[threadIdx.x + 128]);
        atomicAdd(&sums[128 + d], q + lq[threadIdx.x + 128]);
    }
}

// BN (training-mode batch stats) + ReLU, in place
__global__ __launch_bounds__(256) void k_bn_relu(float* __restrict__ V,
                                                 const float* __restrict__ sums,
                                                 const float* __restrict__ gamma,
                                                 const float* __restrict__ beta,
                                                 int n, float invN) {
    int idx = blockIdx.x * 256 + threadIdx.x;
    if (idx >= n * DIM) return;
    int d = idx & 127;
    float mu = sums[d] * invN;
    float var = sums[128 + d] * invN - mu * mu;
    float inv = rsqrtf(var + BN_EPS);
    float scale = gamma[d] * inv;
    float shift = beta[d] - mu * scale;
    float v = V[idx] * scale + shift;
    V[idx] = fmaxf(v, 0.f);
}

// BN + residual + ReLU -> out (element-wise; safe when V == out)
__global__ __launch_bounds__(256) void k_bn_res_relu(const float* __restrict__ V,
                                                     const float* __restrict__ X,
                                                     const float* __restrict__ sums,
                                                     const float* __restrict__ gamma,
                                                     const float* __restrict__ beta,
                                                     float* __restrict__ out,
                                                     int n, float invN) {
    int idx = blockIdx.x * 256 + threadIdx.x;
    if (idx >= n * DIM) return;
    int d = idx & 127;
    float mu = sums[d] * invN;
    float var = sums[128 + d] * invN - mu * mu;
    float inv = rsqrtf(var + BN_EPS);
    float scale = gamma[d] * inv;
    float shift = beta[d] - mu * scale;
    float v = V[idx] * scale + shift + X[idx];
    out[idx] = fmaxf(v, 0.f);
}

// ---------------------------------------------------------------------------
extern "C" void kernel_launch(void* const* d_in, const int* in_sizes, int n_in,
                              void* d_out, int out_size, void* d_ws, size_t ws_size,
                              hipStream_t stream) {
    const float* x      = (const float*)d_in[0];
    const int*   ei     = (const int*)d_in[1];
    const float* W1     = (const float*)d_in[2];
    const float* b1     = (const float*)d_in[3];
    const float* gamma1 = (const float*)d_in[4];
    const float* beta1  = (const float*)d_in[5];
    const float* W2     = (const float*)d_in[6];
    const float* b2     = (const float*)d_in[7];
    const float* gamma2 = (const float*)d_in[8];
    const float* beta2  = (const float*)d_in[9];
    float* out = (float*)d_out;

    int n = in_sizes[0] / DIM;   // 50000
    int e = in_sizes[1] / 2;     // 800000
    const int* srcIdx = ei;       // edge_index[0,:]
    const int* dstIdx = ei + e;   // edge_index[1,:]

    int gN    = (n + 255) / 256;
    int gE    = (e + 255) / 256;
    int gRows = (n + 31) / 32;
    int gNode = (n + 3) / 4;
    int gElem = (n * DIM + 255) / 256;
    float invN = 1.0f / (float)n;

    char* ws = (char*)d_ws;
    size_t off = 0;
    auto alloc = [&](size_t bytes) -> void* {
        void* p = ws + off;
        off += (bytes + 255) & ~(size_t)255;
        return p;
    };
    int*   deg_cnt   = (int*)  alloc((size_t)n * 4);
    float* dinv      = (float*)alloc((size_t)n * 4);
    int*   row_start = (int*)  alloc((size_t)(n + 1) * 4);
    int*   cursor    = (int*)  alloc((size_t)n * 4);
    int*   blk_sum   = (int*)  alloc((size_t)gN * 4);
    int*   blk_off   = (int*)  alloc((size_t)gN * 4);
    int2*  edge      = (int2*) alloc((size_t)e * 8);              // (src, wgt)
    unsigned short* Hb = (unsigned short*)alloc((size_t)n * DIM * 2);  // bf16 H
    float* stats     = (float*)alloc(512 * 4);   // [stats1 | stats2]
    float* stats1 = stats;
    float* stats2 = stats + 256;
    // d_out doubles as the fp32 N x D buffer (fully overwritten at the end,
    // final BN pass is element-wise in-place-safe).
    float* bufB = out;

    // workspace guard: fail cleanly (wrong output) instead of corrupting memory
    if (off > ws_size || gN > 256) return;

    // graph preprocessing: degrees -> dinv -> CSR prefix
    k_init<<<gN, 256, 0, stream>>>(deg_cnt, stats, n);
    k_deg<<<gE, 256, 0, stream>>>(dstIdx, deg_cnt, e);
    k_dinv<<<gN, 256, 0, stream>>>(deg_cnt, dinv, n);
    k_scan1<<<gN, 256, 0, stream>>>(deg_cnt, row_start, blk_sum, n);
    k_scan2<<<1, 256, 0, stream>>>(blk_sum, blk_off, row_start, gN, n);
    k_scan3<<<gN, 256, 0, stream>>>(row_start, blk_off, cursor, n);

    // FUSED: CSR fill (latency-bound) || GEMM1 (VALU-bound) — independent work
    k_fill_gemm<<<gE + gRows, 256, 0, stream>>>(
        srcIdx, dstIdx, dinv, cursor, edge, e, gE,
        x, W1, Hb, n);

    // conv1 aggregation + BN + ReLU
    k_agg<<<gNode, 256, 0, stream>>>((const unsigned int*)Hb, b1, dinv, row_start, edge, bufB, n, e);
    k_stats<<<gN, 256, 0, stream>>>(bufB, stats1, n);
    k_bn_relu<<<gElem, 256, 0, stream>>>(bufB, stats1, gamma1, beta1, n, invN);

    // conv2 + BN + residual + ReLU
    k_gemm<<<gRows, 256, 0, stream>>>(bufB, W2, Hb, n);
    k_agg<<<gNode, 256, 0, stream>>>((const unsigned int*)Hb, b2, dinv, row_start, edge, bufB, n, e);
    k_stats<<<gN, 256, 0, stream>>>(bufB, stats2, n);
    k_bn_res_relu<<<gElem, 256, 0, stream>>>(bufB, x, stats2, gamma2, beta2, out, n, invN);
}